// Round 1
// baseline (5299.680 us; speedup 1.0000x reference)
//
#include <hip/hip_runtime.h>

#define HWsz 16384
#define Wd 128
#define Hd 128

__device__ __forceinline__ float gelu_f(float x){
    return 0.5f * x * (1.0f + erff(x * 0.70710678118654752f));
}

// ---------------- generic 3x3 conv (SAME), 16x16 tile, 3 cin per stage ----------------
template<int OCH, int ACT>
__global__ __launch_bounds__(256) void conv3x3_kernel(
    const float* __restrict__ in, const float* __restrict__ w,
    const float* __restrict__ bias, float* __restrict__ out,
    int cin, int cout)
{
    __shared__ float tile[3][18*18];
    const int tid = threadIdx.x;
    const int lx = tid & 15, ly = tid >> 4;
    const int tix = blockIdx.x & 7, tiy = blockIdx.x >> 3;
    const int oc0 = blockIdx.y * OCH;
    const int b = blockIdx.z;
    const int x0 = tix*16, y0 = tiy*16;

    float acc[OCH];
#pragma unroll
    for (int i=0;i<OCH;i++) acc[i]=0.f;

    const float* inb = in + (size_t)b*cin*HWsz;

    for (int ci0=0; ci0<cin; ci0+=3){
        for (int t=tid; t<3*324; t+=256){
            int cc = t/324, r = t-cc*324;
            int ry = r/18, rx = r-ry*18;
            int gy = y0+ry-1, gx = x0+rx-1;
            float v = 0.f;
            if ((unsigned)gy < (unsigned)Hd && (unsigned)gx < (unsigned)Wd)
                v = inb[(size_t)(ci0+cc)*HWsz + gy*Wd + gx];
            tile[cc][r] = v;
        }
        __syncthreads();
        float v[3][9];
#pragma unroll
        for (int cc=0; cc<3; cc++)
#pragma unroll
            for (int dy=0; dy<3; dy++)
#pragma unroll
                for (int dx=0; dx<3; dx++)
                    v[cc][dy*3+dx] = tile[cc][(ly+dy)*18 + lx+dx];
#pragma unroll
        for (int i=0;i<OCH;i++){
            int oc = oc0+i;
            if (oc < cout){
                const float* wo = w + ((size_t)oc*cin + ci0)*9;   // uniform -> s_load
#pragma unroll
                for (int cc=0; cc<3; cc++)
#pragma unroll
                    for (int k=0;k<9;k++)
                        acc[i] += v[cc][k]*wo[cc*9+k];
            }
        }
        __syncthreads();
    }
    const int oy=y0+ly, ox=x0+lx;
#pragma unroll
    for (int i=0;i<OCH;i++){
        int oc=oc0+i;
        if (oc<cout){
            float r = acc[i];
            if (bias) r += bias[oc];
            if (ACT) r = gelu_f(r);
            out[((size_t)b*cout+oc)*HWsz + oy*Wd + ox] = r;
        }
    }
}

// ---------------- pointwise conv, 32 oc per thread, fused bias/act/residuals ----------------
template<int OCH, int ACT, int RES>
__global__ __launch_bounds__(256) void conv1x1_kernel(
    const float* __restrict__ in, const float* __restrict__ w,
    const float* __restrict__ bias, float* __restrict__ out,
    int cin, int cout,
    const float* __restrict__ res1, const float* __restrict__ res2)
{
    const int p = blockIdx.x*256 + threadIdx.x;
    const int oc0 = blockIdx.y*OCH;
    const int b = blockIdx.z;
    const float* ip = in + (size_t)b*cin*HWsz + p;
    float acc[OCH];
#pragma unroll
    for(int i=0;i<OCH;i++) acc[i]=0.f;
#pragma unroll 4
    for(int ci=0; ci<cin; ++ci){
        float v = ip[(size_t)ci*HWsz];
#pragma unroll
        for(int i=0;i<OCH;i++){
            int oc = oc0+i;
            if (oc<cout) acc[i] += v * w[(size_t)oc*cin + ci];
        }
    }
#pragma unroll
    for(int i=0;i<OCH;i++){
        int oc=oc0+i;
        if(oc<cout){
            float r=acc[i];
            if(bias) r += bias[oc];
            if(ACT) r = gelu_f(r);
            size_t idx = ((size_t)b*cout+oc)*HWsz + p;
            if(RES>=1) r += res1[idx];
            if(RES>=2) r += res2[idx];
            out[idx]=r;
        }
    }
}

// ---------------- channel LayerNorm (per pixel over 96 channels) ----------------
__global__ __launch_bounds__(256) void layernorm_kernel(
    const float* __restrict__ in, const float* __restrict__ w,
    const float* __restrict__ bias, float* __restrict__ out)
{
    const int p = blockIdx.x*256+threadIdx.x;
    const int b = blockIdx.y;
    const float* ip = in + (size_t)b*96*HWsz + p;
    float v[96];
    float s=0.f;
#pragma unroll
    for(int c=0;c<96;c++){ v[c]=ip[(size_t)c*HWsz]; s+=v[c]; }
    const float mu = s*(1.f/96.f);
    float s2=0.f;
#pragma unroll
    for(int c=0;c<96;c++){ float d=v[c]-mu; s2+=d*d; }
    const float inv = 1.f/sqrtf(s2*(1.f/96.f)+1e-5f);
    float* op = out + (size_t)b*96*HWsz + p;
#pragma unroll
    for(int c=0;c<96;c++) op[(size_t)c*HWsz] = (v[c]-mu)*inv*w[c]+bias[c];
}

// ---------------- 3x3 conv with tiny cin (1 or 3) ----------------
template<int CIN, int ACT>
__global__ __launch_bounds__(256) void conv3x3_small_kernel(
    const float* __restrict__ in, const float* __restrict__ w,
    const float* __restrict__ bias, float* __restrict__ out)
{
    const int p = blockIdx.x*256+threadIdx.x;
    const int oc = blockIdx.y;
    const int b = blockIdx.z;
    const int y = p>>7, x = p&127;
    const float* ib = in + (size_t)b*CIN*HWsz;
    float acc = bias[oc];
#pragma unroll
    for(int ci=0;ci<CIN;ci++){
        const float* wp = w + ((size_t)oc*CIN+ci)*9;
        const float* ip = ib + (size_t)ci*HWsz;
#pragma unroll
        for(int dy=0;dy<3;dy++){
            int gy=y+dy-1;
            if((unsigned)gy<128u){
#pragma unroll
                for(int dx=0;dx<3;dx++){
                    int gx=x+dx-1;
                    if((unsigned)gx<128u) acc += ip[gy*Wd+gx]*wp[dy*3+dx];
                }
            }
        }
    }
    if(ACT) acc = gelu_f(acc);
    out[((size_t)b*96+oc)*HWsz + p] = acc;
}

// ---------------- depthwise 3x3 ----------------
__global__ __launch_bounds__(256) void dwconv3x3_kernel(
    const float* __restrict__ in, const float* __restrict__ w,
    float* __restrict__ out, int C)
{
    const int p = blockIdx.x*256+threadIdx.x;
    const int c = blockIdx.y;
    const int b = blockIdx.z;
    const int y=p>>7, x=p&127;
    const float* ip = in + ((size_t)b*C+c)*HWsz;
    const float* wp = w + (size_t)c*9;
    float acc=0.f;
#pragma unroll
    for(int dy=0;dy<3;dy++){
        int gy=y+dy-1;
        if((unsigned)gy<128u){
#pragma unroll
            for(int dx=0;dx<3;dx++){
                int gx=x+dx-1;
                if((unsigned)gx<128u) acc += ip[gy*Wd+gx]*wp[dy*3+dx];
            }
        }
    }
    out[((size_t)b*C+c)*HWsz + p] = acc;
}

// ---------------- row L2-norm reciprocals: inv[r] = 1/max(||row||,1e-12) ----------------
__global__ __launch_bounds__(256) void rownorm_kernel(
    const float* __restrict__ in, float* __restrict__ inv, int cpb, int cstride)
{
    __shared__ float red[256];
    const int r = blockIdx.x;
    const int b = r / cpb, c = r % cpb;
    const float* ip = in + ((size_t)b*cstride + c)*HWsz;
    float s=0.f;
    for(int p=threadIdx.x; p<HWsz; p+=256){ float v=ip[p]; s+=v*v; }
    red[threadIdx.x]=s; __syncthreads();
    for(int st=128; st>0; st>>=1){
        if(threadIdx.x<st) red[threadIdx.x]+=red[threadIdx.x+st];
        __syncthreads();
    }
    if(threadIdx.x==0) inv[r] = 1.f/fmaxf(sqrtf(red[0]), 1e-12f);
}

// ---------------- QK^T partials: deterministic p-split ----------------
__global__ __launch_bounds__(576) void qk_kernel(
    const float* __restrict__ q, const float* __restrict__ kv, float* __restrict__ part)
{
    const int bh = blockIdx.y, b=bh>>2, h=bh&3;
    const int tid = threadIdx.x;
    const int i = tid/24, j = tid - i*24;
    const float4* qp = (const float4*)(q  + ((size_t)b*96  + h*24+i)*HWsz) + blockIdx.x*128;
    const float4* kp = (const float4*)(kv + ((size_t)b*192 + h*24+j)*HWsz) + blockIdx.x*128;
    float acc=0.f;
#pragma unroll 4
    for(int t=0;t<128;t++){
        float4 a=qp[t], c=kp[t];
        acc += a.x*c.x + a.y*c.y + a.z*c.z + a.w*c.w;
    }
    part[((size_t)blockIdx.x*16 + bh)*576 + tid] = acc;
}

__global__ void qk_reduce_kernel(const float* __restrict__ part, float* __restrict__ out)
{
    int idx = blockIdx.x*256+threadIdx.x;
    if(idx < 16*576){
        float s=0.f;
        for(int c=0;c<32;c++) s += part[(size_t)c*(16*576)+idx];
        out[idx]=s;
    }
}

// ---------------- scaled softmax over 24 cols (norms + temp folded in) ----------------
__global__ __launch_bounds__(576) void softmax_kernel(
    const float* __restrict__ raw, const float* __restrict__ invq,
    const float* __restrict__ invk, const float* __restrict__ temp,
    float* __restrict__ attn)
{
    __shared__ float l[576];
    const int bh=blockIdx.x, b=bh>>2, h=bh&3;
    const int tid=threadIdx.x;
    const int i=tid/24, j=tid-i*24;
    l[tid] = raw[(size_t)bh*576+tid] * invq[b*96+h*24+i] * invk[b*96+h*24+j] * temp[h];
    __syncthreads();
    if(tid<24){
        float m=-1e30f;
#pragma unroll
        for(int jj=0;jj<24;jj++) m = fmaxf(m, l[tid*24+jj]);
        float e[24]; float s=0.f;
#pragma unroll
        for(int jj=0;jj<24;jj++){ e[jj]=__expf(l[tid*24+jj]-m); s+=e[jj]; }
        float isv = 1.f/s;
#pragma unroll
        for(int jj=0;jj<24;jj++) attn[(size_t)bh*576 + tid*24 + jj] = e[jj]*isv;
    }
}

// ---------------- out = attn @ v ----------------
__global__ __launch_bounds__(256) void pv_kernel(
    const float* __restrict__ attn, const float* __restrict__ kv, float* __restrict__ out)
{
    const int p = blockIdx.x*256+threadIdx.x;
    const int c = blockIdx.y, b = blockIdx.z;
    const int h = c/24, ci = c - h*24;
    const float* ap = attn + ((size_t)(b*4+h))*576 + ci*24;   // uniform -> s_load
    const float* vp = kv + ((size_t)b*192 + 96 + h*24)*HWsz + p;
    float acc=0.f;
#pragma unroll
    for(int d=0;d<24;d++) acc += ap[d]*vp[(size_t)d*HWsz];
    out[((size_t)b*96+c)*HWsz + p] = acc;
}

extern "C" void kernel_launch(void* const* d_in, const int* in_sizes, int n_in,
                              void* d_out, int out_size, void* d_ws, size_t ws_size,
                              hipStream_t stream)
{
    const float* x     = (const float*)d_in[0];
    const float* Lc_w1 = (const float*)d_in[1];
    const float* Lc_b1 = (const float*)d_in[2];
    const float* Lc_w2 = (const float*)d_in[3];
    const float* Lc_b2 = (const float*)d_in[4];
    const float* Rc_w1 = (const float*)d_in[5];
    const float* Rc_b1 = (const float*)d_in[6];
    const float* Rc_w2 = (const float*)d_in[7];
    const float* Rc_b2 = (const float*)d_in[8];
    const float* Lr_w  = (const float*)d_in[9];
    const float* Lr_b  = (const float*)d_in[10];
    const float* Rr_w  = (const float*)d_in[11];
    const float* Rr_b  = (const float*)d_in[12];
    const float* n1_w  = (const float*)d_in[13];
    const float* n1_b  = (const float*)d_in[14];
    const float* nL_w  = (const float*)d_in[15];
    const float* nL_b  = (const float*)d_in[16];
    const float* n2_w  = (const float*)d_in[17];
    const float* n2_b  = (const float*)d_in[18];
    const float* temp  = (const float*)d_in[19];
    const float* q_w   = (const float*)d_in[20];
    const float* qd_w  = (const float*)d_in[21];
    const float* kv_w  = (const float*)d_in[22];
    const float* kvd_w = (const float*)d_in[23];
    const float* po_w  = (const float*)d_in[24];
    const float* pi_w  = (const float*)d_in[25];
    const float* fdw_w = (const float*)d_in[26];
    const float* fpo_w = (const float*)d_in[27];

    const size_t N96  = (size_t)4*96*HWsz;     // 6,291,456
    const size_t N192 = 2*N96;
    const size_t N255 = (size_t)4*255*HWsz;

    float* ws = (float*)d_ws;
    float* A  = ws;                 // 96ch scratch
    float* Bb = ws + N96;           // R_rein (live to end)
    float* D  = ws + 2*N96;         // q0, then x1
    float* C  = ws + 3*N96;         // ill, then q
    float* E  = ws + 4*N96;         // kv0 (192ch)
    float* F  = ws + 4*N96 + N192;  // kv   (192ch)
    float* G  = C;                  // f0 (255ch) — overlays dead C+E
    float* Hh = F;                  // f1 (255ch) — overlays dead F (+tail)
    float* sm   = ws + 4*N96 + N192 + N255;
    float* invq = sm;               // 384
    float* invk = sm + 384;         // 384
    float* part = sm + 768;         // 32*9216
    float* araw = part + 32*9216;   // 9216
    float* attn = araw + 9216;      // 9216

    float* out_x = (float*)d_out;
    float* out_L = out_x + N96;
    float* out_R = out_L + 4*HWsz;

    dim3 blk(256);

    // Retinex heads
    hipLaunchKernelGGL((conv3x3_kernel<16,1>), dim3(64,6,4), blk, 0, stream, x, Lc_w1, Lc_b1, A, 96, 96);
    hipLaunchKernelGGL((conv1x1_kernel<32,0,0>), dim3(64,1,4), blk, 0, stream, A, Lc_w2, Lc_b2, out_L, 96, 1, nullptr, nullptr);
    hipLaunchKernelGGL((conv3x3_kernel<16,1>), dim3(64,6,4), blk, 0, stream, x, Rc_w1, Rc_b1, A, 96, 96);
    hipLaunchKernelGGL((conv1x1_kernel<32,0,0>), dim3(64,1,4), blk, 0, stream, A, Rc_w2, Rc_b2, out_R, 96, 3, nullptr, nullptr);
    hipLaunchKernelGGL((conv3x3_small_kernel<1,1>), dim3(64,96,4), blk, 0, stream, out_L, Lr_w, Lr_b, A);   // L_rein
    hipLaunchKernelGGL((conv3x3_small_kernel<3,0>), dim3(64,96,4), blk, 0, stream, out_R, Rr_w, Rr_b, Bb);  // R_rein

    // norms
    hipLaunchKernelGGL(layernorm_kernel, dim3(64,4), blk, 0, stream, A, nL_w, nL_b, C);  // ill
    hipLaunchKernelGGL(layernorm_kernel, dim3(64,4), blk, 0, stream, x, n1_w, n1_b, A);  // xn

    // q path
    hipLaunchKernelGGL((conv1x1_kernel<32,0,0>), dim3(64,3,4), blk, 0, stream, C, q_w, nullptr, D, 96, 96, nullptr, nullptr);
    hipLaunchKernelGGL((conv3x3_kernel<16,0>), dim3(64,6,4), blk, 0, stream, D, qd_w, nullptr, C, 96, 96); // q -> C
    // kv path
    hipLaunchKernelGGL((conv1x1_kernel<32,0,0>), dim3(64,6,4), blk, 0, stream, A, kv_w, nullptr, E, 96, 192, nullptr, nullptr);
    hipLaunchKernelGGL(dwconv3x3_kernel, dim3(64,192,4), blk, 0, stream, E, kvd_w, F, 192);                // kv -> F

    // attention
    hipLaunchKernelGGL(rownorm_kernel, dim3(384), blk, 0, stream, C, invq, 96, 96);
    hipLaunchKernelGGL(rownorm_kernel, dim3(384), blk, 0, stream, F, invk, 96, 192);
    hipLaunchKernelGGL(qk_kernel, dim3(32,16), dim3(576), 0, stream, C, F, part);
    hipLaunchKernelGGL(qk_reduce_kernel, dim3(36), blk, 0, stream, part, araw);
    hipLaunchKernelGGL(softmax_kernel, dim3(16), dim3(576), 0, stream, araw, invq, invk, temp, attn);
    hipLaunchKernelGGL(pv_kernel, dim3(64,96,4), blk, 0, stream, attn, F, A);                              // out -> A
    hipLaunchKernelGGL((conv1x1_kernel<32,0,1>), dim3(64,3,4), blk, 0, stream, A, po_w, nullptr, D, 96, 96, x, nullptr); // x1 -> D

    // FFN
    hipLaunchKernelGGL(layernorm_kernel, dim3(64,4), blk, 0, stream, D, n2_w, n2_b, A);                    // x2n -> A
    hipLaunchKernelGGL((conv1x1_kernel<32,0,0>), dim3(64,8,4), blk, 0, stream, A, pi_w, nullptr, G, 96, 255, nullptr, nullptr);
    hipLaunchKernelGGL((conv3x3_kernel<16,1>), dim3(64,16,4), blk, 0, stream, G, fdw_w, nullptr, Hh, 255, 255);          // gelu fused
    hipLaunchKernelGGL((conv1x1_kernel<32,0,2>), dim3(64,3,4), blk, 0, stream, Hh, fpo_w, nullptr, out_x, 255, 96, D, Bb);
}

// Round 2
// 2146.251 us; speedup vs baseline: 2.4693x; 2.4693x over previous
//
#include <hip/hip_runtime.h>

#define HWsz 16384
#define Wd 128
#define Hd 128

typedef unsigned short ushortT;
typedef unsigned int uintT;
typedef __attribute__((ext_vector_type(8))) short short8v;
typedef __attribute__((ext_vector_type(4))) float f32x4;

__device__ __forceinline__ float gelu_f(float x){
    return 0.5f * x * (1.0f + erff(x * 0.70710678118654752f));
}

__device__ __forceinline__ ushortT f2b(float f){
    union { float f; uintT u; } v; v.f = f;
    uintT r = v.u + 0x7FFFu + ((v.u >> 16) & 1u);   // RNE
    return (ushortT)(r >> 16);
}

// ============ weight pack: [oc][cin][3][3] fp32 -> [nt][ch][tap][kg][ocl<BN>][8] bf16 ============
__global__ __launch_bounds__(256) void pack_w_kernel(
    const float* __restrict__ w, ushortT* __restrict__ outp,
    int cout, int cin, int BN, int NCH, int total)
{
    int e = blockIdx.x*256 + threadIdx.x;
    if (e >= total) return;
    int j = e & 7;
    int r = e >> 3;
    int ocl = r % BN; r /= BN;
    int kg  = r & 3;  r >>= 2;
    int tap = r % 9;  r /= 9;
    int ch  = r % NCH;
    int nt  = r / NCH;
    int ci = ch*32 + kg*8 + j;
    int oc = nt*BN + ocl;
    float v = (oc < cout && ci < cin) ? w[((size_t)oc*cin + ci)*9 + tap] : 0.f;
    outp[e] = f2b(v);
}

// ============ x (NCHW fp32, 96ch) -> NHWC bf16 [b][p][96] ============
__global__ __launch_bounds__(256) void tonhwc_kernel(
    const float* __restrict__ in, ushortT* __restrict__ outp)
{
    const int p = blockIdx.x*256 + threadIdx.x;
    const int b = blockIdx.y;
    const float* ip = in + (size_t)b*96*HWsz + p;
    ushortT* op = outp + ((size_t)b*HWsz + p)*96;
#pragma unroll
    for (int half=0; half<2; half++){
        float v[48];
#pragma unroll
        for (int c=0;c<48;c++) v[c] = ip[(size_t)(half*48+c)*HWsz];
#pragma unroll
        for (int i=0;i<48;i+=2){
            uintT pk = (uintT)f2b(v[i]) | ((uintT)f2b(v[i+1])<<16);
            *(uintT*)(op + half*48 + i) = pk;
        }
    }
}

// ============ MFMA implicit-GEMM 3x3 conv (SAME) ============
// in: NHWC bf16 [b][p][Cpad], Cpad = NCH*32.  out: NCHW fp32.
// block: 16x16 pixel tile x BN ocs; 4 waves, each 64px x BN.
template<int NG, int NCH, int ACT>
__global__ __launch_bounds__(256,2) void conv3x3_mfma(
    const ushortT* __restrict__ inh, const ushortT* __restrict__ wpk,
    const float* __restrict__ bias, float* __restrict__ out, int cout)
{
    constexpr int BN = NG*16;
    constexpr int Cpad = NCH*32;
    __shared__ __align__(16) ushortT As[4*324*8];
    __shared__ __align__(16) ushortT Ws[9*4*BN*8];

    const int tid = threadIdx.x;
    const int l   = tid & 63;
    const int wv  = tid >> 6;
    const int l15 = l & 15;
    const int kg  = l >> 4;
    const int tix = blockIdx.x & 7, tiy = blockIdx.x >> 3;
    const int nt  = blockIdx.y;
    const int b   = blockIdx.z;

    f32x4 acc[4][NG];
#pragma unroll
    for (int m=0;m<4;m++)
#pragma unroll
        for (int n=0;n<NG;n++) acc[m][n] = (f32x4){0.f,0.f,0.f,0.f};

    const ushortT* inb = inh + (size_t)b*HWsz*Cpad;

    for (int ch=0; ch<NCH; ch++){
        __syncthreads();
        // ---- stage A: As[kg][p(18x18)][8ci] ----
#pragma unroll
        for (int g=0; g<4; g++){
            for (int p=tid; p<324; p+=256){
                int hy = p/18, hx = p - hy*18;
                int gy = tiy*16 + hy - 1, gx = tix*16 + hx - 1;
                uint4 v; v.x=0u; v.y=0u; v.z=0u; v.w=0u;
                if ((unsigned)gy < 128u && (unsigned)gx < 128u)
                    v = *(const uint4*)(inb + (size_t)(gy*Wd+gx)*Cpad + ch*32 + g*8);
                *(uint4*)(As + (g*324+p)*8) = v;
            }
        }
        // ---- stage W: straight copy of this chunk's packed block ----
        const ushortT* wsrc = wpk + ((size_t)(nt*NCH + ch))*(9*4*BN*8);
        for (int t=tid; t<9*4*BN; t+=256)
            *(uint4*)(Ws + t*8) = *(const uint4*)(wsrc + t*8);
        __syncthreads();
        // ---- 9 taps x K=32 MFMA ----
#pragma unroll
        for (int tp=0; tp<9; tp++){
            const int dy = tp/3, dx = tp - dy*3;
            short8v a[4], bf[NG];
#pragma unroll
            for (int mg=0; mg<4; mg++){
                int p = (wv*4 + mg + dy)*18 + l15 + dx;
                a[mg] = *(const short8v*)(As + (kg*324 + p)*8);
            }
#pragma unroll
            for (int n=0;n<NG;n++)
                bf[n] = *(const short8v*)(Ws + ((tp*4 + kg)*BN + n*16 + l15)*8);
#pragma unroll
            for (int mg=0;mg<4;mg++)
#pragma unroll
                for (int n=0;n<NG;n++)
                    acc[mg][n] = __builtin_amdgcn_mfma_f32_16x16x32_bf16(a[mg], bf[n], acc[mg][n], 0,0,0);
        }
    }
    // ---- epilogue: D row=(lane>>4)*4+j (pixel), col=lane&15 (oc) ----
#pragma unroll
    for (int n=0;n<NG;n++){
        int oc = nt*BN + n*16 + l15;
        if (oc < cout){
            float bs = bias ? bias[oc] : 0.f;
#pragma unroll
            for (int mg=0;mg<4;mg++){
                int gy = tiy*16 + wv*4 + mg;
                int gx = tix*16 + kg*4;
                float4 r;
                r.x = acc[mg][n][0] + bs; r.y = acc[mg][n][1] + bs;
                r.z = acc[mg][n][2] + bs; r.w = acc[mg][n][3] + bs;
                if (ACT){ r.x=gelu_f(r.x); r.y=gelu_f(r.y); r.z=gelu_f(r.z); r.w=gelu_f(r.w); }
                *(float4*)(out + ((size_t)b*cout + oc)*HWsz + gy*Wd + gx) = r;
            }
        }
    }
}

// ============ pointwise conv, fp32, fused bias/act/residuals ============
template<int OCH, int ACT, int RES>
__global__ __launch_bounds__(256) void conv1x1_kernel(
    const float* __restrict__ in, const float* __restrict__ w,
    const float* __restrict__ bias, float* __restrict__ out,
    int cin, int cout,
    const float* __restrict__ res1, const float* __restrict__ res2)
{
    const int p = blockIdx.x*256 + threadIdx.x;
    const int oc0 = blockIdx.y*OCH;
    const int b = blockIdx.z;
    const float* ip = in + (size_t)b*cin*HWsz + p;
    float acc[OCH];
#pragma unroll
    for(int i=0;i<OCH;i++) acc[i]=0.f;
#pragma unroll 4
    for(int ci=0; ci<cin; ++ci){
        float v = ip[(size_t)ci*HWsz];
#pragma unroll
        for(int i=0;i<OCH;i++){
            int oc = oc0+i;
            if (oc<cout) acc[i] += v * w[(size_t)oc*cin + ci];
        }
    }
#pragma unroll
    for(int i=0;i<OCH;i++){
        int oc=oc0+i;
        if(oc<cout){
            float r=acc[i];
            if(bias) r += bias[oc];
            if(ACT) r = gelu_f(r);
            size_t idx = ((size_t)b*cout+oc)*HWsz + p;
            if(RES>=1) r += res1[idx];
            if(RES>=2) r += res2[idx];
            out[idx]=r;
        }
    }
}

// ============ pointwise conv -> NHWC bf16 output (no bias/act) ============
template<int OCH>
__global__ __launch_bounds__(256) void conv1x1_nhwc_kernel(
    const float* __restrict__ in, const float* __restrict__ w,
    ushortT* __restrict__ outp, int cin, int cout, int Cpad)
{
    const int p = blockIdx.x*256 + threadIdx.x;
    const int oc0 = blockIdx.y*OCH;
    const int b = blockIdx.z;
    const float* ip = in + (size_t)b*cin*HWsz + p;
    float acc[OCH];
#pragma unroll
    for(int i=0;i<OCH;i++) acc[i]=0.f;
#pragma unroll 4
    for(int ci=0; ci<cin; ++ci){
        float v = ip[(size_t)ci*HWsz];
#pragma unroll
        for(int i=0;i<OCH;i++){
            int oc = oc0+i;
            if (oc<cout) acc[i] += v * w[(size_t)oc*cin + ci];
        }
    }
    ushortT* op = outp + ((size_t)b*HWsz + p)*Cpad + oc0;
#pragma unroll
    for(int i=0;i<OCH;i+=2){
        float r0 = (oc0+i   < cout) ? acc[i]   : 0.f;
        float r1 = (oc0+i+1 < cout) ? acc[i+1] : 0.f;
        uintT pk = (uintT)f2b(r0) | ((uintT)f2b(r1)<<16);
        *(uintT*)(op + i) = pk;
    }
}

// ============ channel LayerNorm (per pixel over 96 channels) ============
__global__ __launch_bounds__(256) void layernorm_kernel(
    const float* __restrict__ in, const float* __restrict__ w,
    const float* __restrict__ bias, float* __restrict__ out)
{
    const int p = blockIdx.x*256+threadIdx.x;
    const int b = blockIdx.y;
    const float* ip = in + (size_t)b*96*HWsz + p;
    float v[96];
    float s=0.f;
#pragma unroll
    for(int c=0;c<96;c++){ v[c]=ip[(size_t)c*HWsz]; s+=v[c]; }
    const float mu = s*(1.f/96.f);
    float s2=0.f;
#pragma unroll
    for(int c=0;c<96;c++){ float d=v[c]-mu; s2+=d*d; }
    const float inv = 1.f/sqrtf(s2*(1.f/96.f)+1e-5f);
    float* op = out + (size_t)b*96*HWsz + p;
#pragma unroll
    for(int c=0;c<96;c++) op[(size_t)c*HWsz] = (v[c]-mu)*inv*w[c]+bias[c];
}

// ============ 3x3 conv with tiny cin (1 or 3) ============
template<int CIN, int ACT>
__global__ __launch_bounds__(256) void conv3x3_small_kernel(
    const float* __restrict__ in, const float* __restrict__ w,
    const float* __restrict__ bias, float* __restrict__ out)
{
    const int p = blockIdx.x*256+threadIdx.x;
    const int oc = blockIdx.y;
    const int b = blockIdx.z;
    const int y = p>>7, x = p&127;
    const float* ib = in + (size_t)b*CIN*HWsz;
    float acc = bias[oc];
#pragma unroll
    for(int ci=0;ci<CIN;ci++){
        const float* wp = w + ((size_t)oc*CIN+ci)*9;
        const float* ip = ib + (size_t)ci*HWsz;
#pragma unroll
        for(int dy=0;dy<3;dy++){
            int gy=y+dy-1;
            if((unsigned)gy<128u){
#pragma unroll
                for(int dx=0;dx<3;dx++){
                    int gx=x+dx-1;
                    if((unsigned)gx<128u) acc += ip[gy*Wd+gx]*wp[dy*3+dx];
                }
            }
        }
    }
    if(ACT) acc = gelu_f(acc);
    out[((size_t)b*96+oc)*HWsz + p] = acc;
}

// ============ depthwise 3x3 ============
__global__ __launch_bounds__(256) void dwconv3x3_kernel(
    const float* __restrict__ in, const float* __restrict__ w,
    float* __restrict__ out, int C)
{
    const int p = blockIdx.x*256+threadIdx.x;
    const int c = blockIdx.y;
    const int b = blockIdx.z;
    const int y=p>>7, x=p&127;
    const float* ip = in + ((size_t)b*C+c)*HWsz;
    const float* wp = w + (size_t)c*9;
    float acc=0.f;
#pragma unroll
    for(int dy=0;dy<3;dy++){
        int gy=y+dy-1;
        if((unsigned)gy<128u){
#pragma unroll
            for(int dx=0;dx<3;dx++){
                int gx=x+dx-1;
                if((unsigned)gx<128u) acc += ip[gy*Wd+gx]*wp[dy*3+dx];
            }
        }
    }
    out[((size_t)b*C+c)*HWsz + p] = acc;
}

// ============ row L2-norm reciprocals ============
__global__ __launch_bounds__(256) void rownorm_kernel(
    const float* __restrict__ in, float* __restrict__ inv, int cpb, int cstride)
{
    __shared__ float red[256];
    const int r = blockIdx.x;
    const int b = r / cpb, c = r % cpb;
    const float* ip = in + ((size_t)b*cstride + c)*HWsz;
    float s=0.f;
    for(int p=threadIdx.x; p<HWsz; p+=256){ float v=ip[p]; s+=v*v; }
    red[threadIdx.x]=s; __syncthreads();
    for(int st=128; st>0; st>>=1){
        if(threadIdx.x<st) red[threadIdx.x]+=red[threadIdx.x+st];
        __syncthreads();
    }
    if(threadIdx.x==0) inv[r] = 1.f/fmaxf(sqrtf(red[0]), 1e-12f);
}

// ============ QK^T partials ============
__global__ __launch_bounds__(576) void qk_kernel(
    const float* __restrict__ q, const float* __restrict__ kv, float* __restrict__ part)
{
    const int bh = blockIdx.y, b=bh>>2, h=bh&3;
    const int tid = threadIdx.x;
    const int i = tid/24, j = tid - i*24;
    const float4* qp = (const float4*)(q  + ((size_t)b*96  + h*24+i)*HWsz) + blockIdx.x*128;
    const float4* kp = (const float4*)(kv + ((size_t)b*192 + h*24+j)*HWsz) + blockIdx.x*128;
    float acc=0.f;
#pragma unroll 4
    for(int t=0;t<128;t++){
        float4 a=qp[t], c=kp[t];
        acc += a.x*c.x + a.y*c.y + a.z*c.z + a.w*c.w;
    }
    part[((size_t)blockIdx.x*16 + bh)*576 + tid] = acc;
}

__global__ void qk_reduce_kernel(const float* __restrict__ part, float* __restrict__ out)
{
    int idx = blockIdx.x*256+threadIdx.x;
    if(idx < 16*576){
        float s=0.f;
        for(int c=0;c<32;c++) s += part[(size_t)c*(16*576)+idx];
        out[idx]=s;
    }
}

// ============ softmax over 24 cols (norms + temp folded) ============
__global__ __launch_bounds__(576) void softmax_kernel(
    const float* __restrict__ raw, const float* __restrict__ invq,
    const float* __restrict__ invk, const float* __restrict__ temp,
    float* __restrict__ attn)
{
    __shared__ float l[576];
    const int bh=blockIdx.x, b=bh>>2, h=bh&3;
    const int tid=threadIdx.x;
    const int i=tid/24, j=tid-i*24;
    l[tid] = raw[(size_t)bh*576+tid] * invq[b*96+h*24+i] * invk[b*96+h*24+j] * temp[h];
    __syncthreads();
    if(tid<24){
        float m=-1e30f;
#pragma unroll
        for(int jj=0;jj<24;jj++) m = fmaxf(m, l[tid*24+jj]);
        float e[24]; float s=0.f;
#pragma unroll
        for(int jj=0;jj<24;jj++){ e[jj]=__expf(l[tid*24+jj]-m); s+=e[jj]; }
        float isv = 1.f/s;
#pragma unroll
        for(int jj=0;jj<24;jj++) attn[(size_t)bh*576 + tid*24 + jj] = e[jj]*isv;
    }
}

// ============ out = attn @ v ============
__global__ __launch_bounds__(256) void pv_kernel(
    const float* __restrict__ attn, const float* __restrict__ kv, float* __restrict__ out)
{
    const int p = blockIdx.x*256+threadIdx.x;
    const int c = blockIdx.y, b = blockIdx.z;
    const int h = c/24, ci = c - h*24;
    const float* ap = attn + ((size_t)(b*4+h))*576 + ci*24;
    const float* vp = kv + ((size_t)b*192 + 96 + h*24)*HWsz + p;
    float acc=0.f;
#pragma unroll
    for(int d=0;d<24;d++) acc += ap[d]*vp[(size_t)d*HWsz];
    out[((size_t)b*96+c)*HWsz + p] = acc;
}

extern "C" void kernel_launch(void* const* d_in, const int* in_sizes, int n_in,
                              void* d_out, int out_size, void* d_ws, size_t ws_size,
                              hipStream_t stream)
{
    const float* x     = (const float*)d_in[0];
    const float* Lc_w1 = (const float*)d_in[1];
    const float* Lc_b1 = (const float*)d_in[2];
    const float* Lc_w2 = (const float*)d_in[3];
    const float* Lc_b2 = (const float*)d_in[4];
    const float* Rc_w1 = (const float*)d_in[5];
    const float* Rc_b1 = (const float*)d_in[6];
    const float* Rc_w2 = (const float*)d_in[7];
    const float* Rc_b2 = (const float*)d_in[8];
    const float* Lr_w  = (const float*)d_in[9];
    const float* Lr_b  = (const float*)d_in[10];
    const float* Rr_w  = (const float*)d_in[11];
    const float* Rr_b  = (const float*)d_in[12];
    const float* n1_w  = (const float*)d_in[13];
    const float* n1_b  = (const float*)d_in[14];
    const float* nL_w  = (const float*)d_in[15];
    const float* nL_b  = (const float*)d_in[16];
    const float* n2_w  = (const float*)d_in[17];
    const float* n2_b  = (const float*)d_in[18];
    const float* temp  = (const float*)d_in[19];
    const float* q_w   = (const float*)d_in[20];
    const float* qd_w  = (const float*)d_in[21];
    const float* kv_w  = (const float*)d_in[22];
    const float* kvd_w = (const float*)d_in[23];
    const float* po_w  = (const float*)d_in[24];
    const float* pi_w  = (const float*)d_in[25];
    const float* fdw_w = (const float*)d_in[26];
    const float* fpo_w = (const float*)d_in[27];

    const size_t N96  = (size_t)4*96*HWsz;     // 6,291,456 floats
    const size_t N255 = (size_t)4*255*HWsz;    // 16,711,680 floats

    float* ws = (float*)d_ws;
    float* A  = ws;                 // 96ch fp32 scratch
    float* Bb = ws + N96;           // R_rein (live to end)
    float* D  = ws + 2*N96;         // x1 (written late)
    float* C  = ws + 3*N96;         // ill, then q
    float* E  = ws + 4*N96;         // kv0 (192ch)
    float* F  = ws + 6*N96;         // kv (192ch)
    float* Hh = F;                  // fdw out (255ch) overlays F (+tail)
    float* sm   = ws + 6*N96 + N255;
    float* invq = sm;               // 384
    float* invk = sm + 384;         // 384
    float* part = sm + 768;         // 32*9216
    float* araw = part + 32*9216;   // 9216
    float* attn = araw + 9216;      // 9216
    // bf16 overlays (time-disjoint with their fp32 hosts)
    ushortT* xh  = (ushortT*)(ws + 2*N96);             // 12.6MB in D (dead before D written)
    ushortT* q0h = (ushortT*)(ws + 2*N96) + 6291456;   // next 12.6MB of D
    ushortT* f0h = (ushortT*)(ws + 3*N96);             // 33.5MB over C+E (both dead by then)
    ushortT* wpkL = (ushortT*)(attn + 9216 + 16);
    ushortT* wpkR = wpkL + 82944;
    ushortT* wpkQ = wpkR + 82944;
    ushortT* wpkF = wpkQ + 82944;

    float* out_x = (float*)d_out;
    float* out_L = out_x + N96;
    float* out_R = out_L + 4*HWsz;

    dim3 blk(256);

    // ---- weight packing + input convert (independent, front of graph) ----
    hipLaunchKernelGGL(pack_w_kernel, dim3((82944+255)/256), blk, 0, stream, Lc_w1, wpkL, 96, 96, 48, 3, 82944);
    hipLaunchKernelGGL(pack_w_kernel, dim3((82944+255)/256), blk, 0, stream, Rc_w1, wpkR, 96, 96, 48, 3, 82944);
    hipLaunchKernelGGL(pack_w_kernel, dim3((82944+255)/256), blk, 0, stream, qd_w,  wpkQ, 96, 96, 48, 3, 82944);
    hipLaunchKernelGGL(pack_w_kernel, dim3((589824+255)/256), blk, 0, stream, fdw_w, wpkF, 255, 255, 64, 8, 589824);
    hipLaunchKernelGGL(tonhwc_kernel, dim3(64,4), blk, 0, stream, x, xh);

    // ---- Retinex heads ----
    hipLaunchKernelGGL((conv3x3_mfma<3,3,1>), dim3(64,2,4), blk, 0, stream, xh, wpkL, Lc_b1, A, 96);
    hipLaunchKernelGGL((conv1x1_kernel<32,0,0>), dim3(64,1,4), blk, 0, stream, A, Lc_w2, Lc_b2, out_L, 96, 1, nullptr, nullptr);
    hipLaunchKernelGGL((conv3x3_mfma<3,3,1>), dim3(64,2,4), blk, 0, stream, xh, wpkR, Rc_b1, A, 96);
    hipLaunchKernelGGL((conv1x1_kernel<32,0,0>), dim3(64,1,4), blk, 0, stream, A, Rc_w2, Rc_b2, out_R, 96, 3, nullptr, nullptr);
    hipLaunchKernelGGL((conv3x3_small_kernel<1,1>), dim3(64,96,4), blk, 0, stream, out_L, Lr_w, Lr_b, A);   // L_rein
    hipLaunchKernelGGL((conv3x3_small_kernel<3,0>), dim3(64,96,4), blk, 0, stream, out_R, Rr_w, Rr_b, Bb);  // R_rein

    // ---- norms ----
    hipLaunchKernelGGL(layernorm_kernel, dim3(64,4), blk, 0, stream, A, nL_w, nL_b, C);  // ill
    hipLaunchKernelGGL(layernorm_kernel, dim3(64,4), blk, 0, stream, x, n1_w, n1_b, A);  // xn

    // ---- q path ----
    hipLaunchKernelGGL((conv1x1_nhwc_kernel<32>), dim3(64,3,4), blk, 0, stream, C, q_w, q0h, 96, 96, 96);
    hipLaunchKernelGGL((conv3x3_mfma<3,3,0>), dim3(64,2,4), blk, 0, stream, q0h, wpkQ, nullptr, C, 96);  // q -> C
    // ---- kv path ----
    hipLaunchKernelGGL((conv1x1_kernel<32,0,0>), dim3(64,6,4), blk, 0, stream, A, kv_w, nullptr, E, 96, 192, nullptr, nullptr);
    hipLaunchKernelGGL(dwconv3x3_kernel, dim3(64,192,4), blk, 0, stream, E, kvd_w, F, 192);  // kv -> F

    // ---- attention ----
    hipLaunchKernelGGL(rownorm_kernel, dim3(384), blk, 0, stream, C, invq, 96, 96);
    hipLaunchKernelGGL(rownorm_kernel, dim3(384), blk, 0, stream, F, invk, 96, 192);
    hipLaunchKernelGGL(qk_kernel, dim3(32,16), dim3(576), 0, stream, C, F, part);
    hipLaunchKernelGGL(qk_reduce_kernel, dim3(36), blk, 0, stream, part, araw);
    hipLaunchKernelGGL(softmax_kernel, dim3(16), dim3(576), 0, stream, araw, invq, invk, temp, attn);
    hipLaunchKernelGGL(pv_kernel, dim3(64,96,4), blk, 0, stream, attn, F, A);  // out -> A
    hipLaunchKernelGGL((conv1x1_kernel<32,0,1>), dim3(64,3,4), blk, 0, stream, A, po_w, nullptr, D, 96, 96, x, nullptr); // x1 -> D

    // ---- FFN ----
    hipLaunchKernelGGL(layernorm_kernel, dim3(64,4), blk, 0, stream, D, n2_w, n2_b, A);  // x2n -> A
    hipLaunchKernelGGL((conv1x1_nhwc_kernel<32>), dim3(64,8,4), blk, 0, stream, A, pi_w, f0h, 96, 255, 256);
    hipLaunchKernelGGL((conv3x3_mfma<4,8,1>), dim3(64,4,4), blk, 0, stream, f0h, wpkF, nullptr, Hh, 255); // gelu fused
    hipLaunchKernelGGL((conv1x1_kernel<32,0,2>), dim3(64,3,4), blk, 0, stream, Hh, fpo_w, nullptr, out_x, 255, 96, D, Bb);
}

// Round 3
// 605.041 us; speedup vs baseline: 8.7592x; 3.5473x over previous
//
#include <hip/hip_runtime.h>

#define HWsz 16384
#define Wd 128
#define Hd 128

typedef unsigned short ushortT;
typedef unsigned int uintT;
typedef __attribute__((ext_vector_type(8))) short short8v;
typedef __attribute__((ext_vector_type(4))) float f32x4;

__device__ __forceinline__ float gelu_f(float x){
    return 0.5f * x * (1.0f + erff(x * 0.70710678118654752f));
}
__device__ __forceinline__ ushortT f2b(float f){
    union { float f; uintT u; } v; v.f = f;
    uintT r = v.u + 0x7FFFu + ((v.u >> 16) & 1u);   // RNE
    return (ushortT)(r >> 16);
}
__device__ __forceinline__ float b2f(ushortT u){
    union { uintT u; float f; } v; v.u = ((uintT)u) << 16; return v.f;
}

// ============ pack 3x3 weights: [oc][cin][3][3] -> [nt][ch][tap][kg][ocl<BN>][8] bf16 ============
__global__ __launch_bounds__(256) void pack_w_kernel(
    const float* __restrict__ w, ushortT* __restrict__ outp,
    int cout, int cin, int BN, int NCH, int total)
{
    int e = blockIdx.x*256 + threadIdx.x;
    if (e >= total) return;
    int j = e & 7;
    int r = e >> 3;
    int ocl = r % BN; r /= BN;
    int kg  = r & 3;  r >>= 2;
    int tap = r % 9;  r /= 9;
    int ch  = r % NCH;
    int nt  = r / NCH;
    int ci = ch*32 + kg*8 + j;
    int oc = nt*BN + ocl;
    float v = (oc < cout && ci < cin) ? w[((size_t)oc*cin + ci)*9 + tap] : 0.f;
    outp[e] = f2b(v);
}

// ============ pack 1x1 weights: [oc][cin] -> [nt][ch][kg][ocl<BN>][8] bf16 ============
__global__ __launch_bounds__(256) void pack_w1_kernel(
    const float* __restrict__ w, ushortT* __restrict__ outp,
    int cout, int cin, int BN, int NCH, int total)
{
    int e = blockIdx.x*256 + threadIdx.x;
    if (e >= total) return;
    int j = e & 7;
    int r = e >> 3;
    int ocl = r % BN; r /= BN;
    int kg  = r & 3;  r >>= 2;
    int ch  = r % NCH;
    int nt  = r / NCH;
    int ci = ch*32 + kg*8 + j;
    int oc = nt*BN + ocl;
    float v = (oc < cout && ci < cin) ? w[(size_t)oc*cin + ci] : 0.f;
    outp[e] = f2b(v);
}

// ============ x (NCHW fp32, 96ch) -> NHWC bf16 [b][p][96] ============
__global__ __launch_bounds__(256) void tonhwc_kernel(
    const float* __restrict__ in, ushortT* __restrict__ outp)
{
    const int p = blockIdx.x*256 + threadIdx.x;
    const int b = blockIdx.y;
    const float* ip = in + (size_t)b*96*HWsz + p;
    ushortT* op = outp + ((size_t)b*HWsz + p)*96;
#pragma unroll
    for (int g=0; g<12; g++){
        float v[8];
#pragma unroll
        for (int c=0;c<8;c++) v[c] = ip[(size_t)(g*8+c)*HWsz];
        uint4 pk;
        pk.x = (uintT)f2b(v[0]) | ((uintT)f2b(v[1])<<16);
        pk.y = (uintT)f2b(v[2]) | ((uintT)f2b(v[3])<<16);
        pk.z = (uintT)f2b(v[4]) | ((uintT)f2b(v[5])<<16);
        pk.w = (uintT)f2b(v[6]) | ((uintT)f2b(v[7])<<16);
        *(uint4*)(op + g*8) = pk;
    }
}

// ============ MFMA implicit-GEMM 3x3 conv (SAME) ============
// in: NHWC bf16 [b][p][Cpad]; out: OMODE0 NCHW fp32, OMODE1 NHWC bf16 [b][p][ocpad]
template<int NG, int NCH, int ACT, int OMODE>
__global__ __launch_bounds__(256,2) void conv3x3_mfma(
    const ushortT* __restrict__ inh, const ushortT* __restrict__ wpk,
    const float* __restrict__ bias, void* __restrict__ outv, int cout, int ocpad)
{
    constexpr int BN = NG*16;
    constexpr int Cpad = NCH*32;
    __shared__ __align__(16) ushortT As[4*324*8];
    __shared__ __align__(16) ushortT Ws[9*4*BN*8];

    const int tid = threadIdx.x;
    const int l   = tid & 63;
    const int wv  = tid >> 6;
    const int l15 = l & 15;
    const int kg  = l >> 4;
    const int tix = blockIdx.x & 7, tiy = blockIdx.x >> 3;
    const int nt  = blockIdx.y;
    const int b   = blockIdx.z;

    f32x4 acc[4][NG];
#pragma unroll
    for (int m=0;m<4;m++)
#pragma unroll
        for (int n=0;n<NG;n++) acc[m][n] = (f32x4){0.f,0.f,0.f,0.f};

    const ushortT* inb = inh + (size_t)b*HWsz*Cpad;

    for (int ch=0; ch<NCH; ch++){
        __syncthreads();
#pragma unroll
        for (int g=0; g<4; g++){
            for (int p=tid; p<324; p+=256){
                int hy = p/18, hx = p - hy*18;
                int gy = tiy*16 + hy - 1, gx = tix*16 + hx - 1;
                uint4 v; v.x=0u; v.y=0u; v.z=0u; v.w=0u;
                if ((unsigned)gy < 128u && (unsigned)gx < 128u)
                    v = *(const uint4*)(inb + (size_t)(gy*Wd+gx)*Cpad + ch*32 + g*8);
                *(uint4*)(As + (g*324+p)*8) = v;
            }
        }
        const ushortT* wsrc = wpk + ((size_t)(nt*NCH + ch))*(9*4*BN*8);
        for (int t=tid; t<9*4*BN; t+=256)
            *(uint4*)(Ws + t*8) = *(const uint4*)(wsrc + t*8);
        __syncthreads();
#pragma unroll
        for (int tp=0; tp<9; tp++){
            const int dy = tp/3, dx = tp - dy*3;
            short8v a[4], bf[NG];
#pragma unroll
            for (int mg=0; mg<4; mg++){
                int p = (wv*4 + mg + dy)*18 + l15 + dx;
                a[mg] = *(const short8v*)(As + (kg*324 + p)*8);
            }
#pragma unroll
            for (int n=0;n<NG;n++)
                bf[n] = *(const short8v*)(Ws + ((tp*4 + kg)*BN + n*16 + l15)*8);
#pragma unroll
            for (int mg=0;mg<4;mg++)
#pragma unroll
                for (int n=0;n<NG;n++)
                    acc[mg][n] = __builtin_amdgcn_mfma_f32_16x16x32_bf16(a[mg], bf[n], acc[mg][n], 0,0,0);
        }
    }
    // epilogue: D col=lane&15 (oc), row=(lane>>4)*4+j : gy=tiy*16+wv*4+mg, gx=tix*16+kg*4+j
    if (OMODE == 0){
        float* out = (float*)outv;
#pragma unroll
        for (int n=0;n<NG;n++){
            int oc = nt*BN + n*16 + l15;
            if (oc < cout){
                float bs = bias ? bias[oc] : 0.f;
#pragma unroll
                for (int mg=0;mg<4;mg++){
                    int gy = tiy*16 + wv*4 + mg;
                    int gx = tix*16 + kg*4;
                    float4 r;
                    r.x = acc[mg][n][0] + bs; r.y = acc[mg][n][1] + bs;
                    r.z = acc[mg][n][2] + bs; r.w = acc[mg][n][3] + bs;
                    if (ACT){ r.x=gelu_f(r.x); r.y=gelu_f(r.y); r.z=gelu_f(r.z); r.w=gelu_f(r.w); }
                    *(float4*)(out + ((size_t)b*cout + oc)*HWsz + gy*Wd + gx) = r;
                }
            }
        }
    } else {
        ushortT* out = (ushortT*)outv;
#pragma unroll
        for (int n=0;n<NG;n++){
            int oc = nt*BN + n*16 + l15;
            float bs = (bias && oc < cout) ? bias[oc] : 0.f;
#pragma unroll
            for (int mg=0;mg<4;mg++){
                int gy = tiy*16 + wv*4 + mg;
                int gx = tix*16 + kg*4;
#pragma unroll
                for (int j=0;j<4;j++){
                    float r = 0.f;
                    if (oc < cout){
                        r = acc[mg][n][j] + bs;
                        if (ACT) r = gelu_f(r);
                    }
                    out[((size_t)b*HWsz + gy*Wd + gx + j)*ocpad + oc] = f2b(r);
                }
            }
        }
    }
}

// ============ MFMA 1x1 GEMM: no LDS, no barriers ============
// in NHWC bf16 [b][p][Cpad=NCH*32]; W packed [nt][ch][kg][BN][8] (+ per-b stride)
template<int NG, int NCH, int RES, int OMODE>
__global__ __launch_bounds__(256) void gemm1x1_mfma(
    const ushortT* __restrict__ inh, const ushortT* __restrict__ wpk, int wstride_z,
    const float* __restrict__ res1, const float* __restrict__ res2,
    void* __restrict__ outv, int cout, int ocpad)
{
    constexpr int BN = NG*16;
    constexpr int Cpad = NCH*32;
    const int tid = threadIdx.x;
    const int l = tid & 63, wv = tid >> 6, l15 = l & 15, kg = l >> 4;
    const int nt = blockIdx.y, b = blockIdx.z;
    const int p0 = blockIdx.x*256 + wv*64;
    const ushortT* inb = inh + (size_t)b*HWsz*Cpad;
    const ushortT* wp  = wpk + (size_t)b*wstride_z;

    f32x4 acc[4][NG];
#pragma unroll
    for (int m=0;m<4;m++)
#pragma unroll
        for (int n=0;n<NG;n++) acc[m][n] = (f32x4){0.f,0.f,0.f,0.f};

#pragma unroll
    for (int ch=0; ch<NCH; ch++){
        short8v a[4], bw[NG];
#pragma unroll
        for (int mg=0; mg<4; mg++)
            a[mg] = *(const short8v*)(inb + (size_t)(p0 + mg*16 + l15)*Cpad + ch*32 + kg*8);
#pragma unroll
        for (int n=0;n<NG;n++)
            bw[n] = *(const short8v*)(wp + (((size_t)(nt*NCH + ch)*4 + kg)*BN + n*16 + l15)*8);
#pragma unroll
        for (int mg=0;mg<4;mg++)
#pragma unroll
            for (int n=0;n<NG;n++)
                acc[mg][n] = __builtin_amdgcn_mfma_f32_16x16x32_bf16(a[mg], bw[n], acc[mg][n], 0,0,0);
    }
    if (OMODE == 0){
        float* out = (float*)outv;
#pragma unroll
        for (int n=0;n<NG;n++){
            int oc = nt*BN + n*16 + l15;
            if (oc < cout){
#pragma unroll
                for (int mg=0;mg<4;mg++){
                    int pix = p0 + mg*16 + kg*4;
                    size_t idx = ((size_t)b*cout + oc)*HWsz + pix;
                    float4 r;
                    r.x = acc[mg][n][0]; r.y = acc[mg][n][1];
                    r.z = acc[mg][n][2]; r.w = acc[mg][n][3];
                    if (RES>=1){ float4 q = *(const float4*)(res1+idx); r.x+=q.x;r.y+=q.y;r.z+=q.z;r.w+=q.w; }
                    if (RES>=2){ float4 q = *(const float4*)(res2+idx); r.x+=q.x;r.y+=q.y;r.z+=q.z;r.w+=q.w; }
                    *(float4*)(out + idx) = r;
                }
            }
        }
    } else {
        ushortT* out = (ushortT*)outv;
#pragma unroll
        for (int n=0;n<NG;n++){
            int oc = nt*BN + n*16 + l15;
#pragma unroll
            for (int mg=0;mg<4;mg++){
                int pix = p0 + mg*16 + kg*4;
#pragma unroll
                for (int j=0;j<4;j++){
                    float r = (oc < cout) ? acc[mg][n][j] : 0.f;
                    out[((size_t)b*HWsz + pix + j)*ocpad + oc] = f2b(r);
                }
            }
        }
    }
}

// ============ head 1x1 (96 -> NOUT small), NHWC bf16 in, NCHW fp32 out ============
template<int NOUT>
__global__ __launch_bounds__(256) void head1x1_kernel(
    const ushortT* __restrict__ inh, const float* __restrict__ w,
    const float* __restrict__ bias, float* __restrict__ out)
{
    __shared__ float lw[NOUT*96];
    const int tid = threadIdx.x;
    for (int t=tid; t<NOUT*96; t+=256) lw[t] = w[t];
    __syncthreads();
    const int p = blockIdx.x*256 + tid;
    const int b = blockIdx.y;
    const ushortT* ip = inh + ((size_t)b*HWsz + p)*96;
    float v[96];
#pragma unroll
    for (int g=0; g<12; g++){
        short8v s = *(const short8v*)(ip + g*8);
#pragma unroll
        for (int i=0;i<8;i++) v[g*8+i] = b2f((ushortT)s[i]);
    }
#pragma unroll
    for (int oc=0; oc<NOUT; oc++){
        float acc = bias[oc];
#pragma unroll
        for (int c=0;c<96;c++) acc += v[c]*lw[oc*96+c];
        out[((size_t)b*NOUT + oc)*HWsz + p] = acc;
    }
}

// ============ fused: Lr conv3x3(1->96)+bias+GELU, then LayerNorm(nL) -> illh NHWC bf16 ============
__global__ __launch_bounds__(256) void lrein_ln_kernel(
    const float* __restrict__ L, const float* __restrict__ w,
    const float* __restrict__ bias, const float* __restrict__ lnw,
    const float* __restrict__ lnb, ushortT* __restrict__ outh)
{
    __shared__ float sw[864], sb[96], sn1[96], sn2[96];
    const int tid = threadIdx.x;
    for (int t=tid; t<864; t+=256) sw[t] = w[t];
    if (tid < 96){ sb[tid]=bias[tid]; sn1[tid]=lnw[tid]; sn2[tid]=lnb[tid]; }
    __syncthreads();
    const int p = blockIdx.x*256 + tid;
    const int b = blockIdx.y;
    const int y = p>>7, x = p&127;
    const float* ib = L + (size_t)b*HWsz;
    float win[9];
#pragma unroll
    for (int dy=0;dy<3;dy++)
#pragma unroll
        for (int dx=0;dx<3;dx++){
            int gy=y+dy-1, gx=x+dx-1;
            win[dy*3+dx] = ((unsigned)gy<128u && (unsigned)gx<128u) ? ib[gy*Wd+gx] : 0.f;
        }
    float v[96]; float s=0.f;
#pragma unroll
    for (int c=0;c<96;c++){
        float a = sb[c];
#pragma unroll
        for (int t=0;t<9;t++) a += win[t]*sw[c*9+t];
        a = gelu_f(a);
        v[c]=a; s+=a;
    }
    const float mu = s*(1.f/96.f);
    float s2=0.f;
#pragma unroll
    for (int c=0;c<96;c++){ float d=v[c]-mu; s2+=d*d; }
    const float inv = 1.f/sqrtf(s2*(1.f/96.f)+1e-5f);
    ushortT* op = outh + ((size_t)b*HWsz + p)*96;
#pragma unroll
    for (int g=0; g<12; g++){
        uint4 pk; uintT w4[4];
#pragma unroll
        for (int i=0;i<4;i++){
            float r0 = (v[g*8+2*i]-mu)*inv*sn1[g*8+2*i]+sn2[g*8+2*i];
            float r1 = (v[g*8+2*i+1]-mu)*inv*sn1[g*8+2*i+1]+sn2[g*8+2*i+1];
            w4[i] = (uintT)f2b(r0) | ((uintT)f2b(r1)<<16);
        }
        pk.x=w4[0]; pk.y=w4[1]; pk.z=w4[2]; pk.w=w4[3];
        *(uint4*)(op + g*8) = pk;
    }
}

// ============ LayerNorm: NCHW fp32 in -> NHWC bf16 out ============
__global__ __launch_bounds__(256) void ln_n2n_kernel(
    const float* __restrict__ in, const float* __restrict__ w,
    const float* __restrict__ bias, ushortT* __restrict__ outh)
{
    const int p = blockIdx.x*256+threadIdx.x;
    const int b = blockIdx.y;
    const float* ip = in + (size_t)b*96*HWsz + p;
    float v[96]; float s=0.f;
#pragma unroll
    for(int c=0;c<96;c++){ v[c]=ip[(size_t)c*HWsz]; s+=v[c]; }
    const float mu = s*(1.f/96.f);
    float s2=0.f;
#pragma unroll
    for(int c=0;c<96;c++){ float d=v[c]-mu; s2+=d*d; }
    const float inv = 1.f/sqrtf(s2*(1.f/96.f)+1e-5f);
    ushortT* op = outh + ((size_t)b*HWsz + p)*96;
#pragma unroll
    for (int g=0; g<12; g++){
        uint4 pk; uintT w4[4];
#pragma unroll
        for (int i=0;i<4;i++){
            float r0 = (v[g*8+2*i]-mu)*inv*w[g*8+2*i]+bias[g*8+2*i];
            float r1 = (v[g*8+2*i+1]-mu)*inv*w[g*8+2*i+1]+bias[g*8+2*i+1];
            w4[i] = (uintT)f2b(r0) | ((uintT)f2b(r1)<<16);
        }
        pk.x=w4[0]; pk.y=w4[1]; pk.z=w4[2]; pk.w=w4[3];
        *(uint4*)(op + g*8) = pk;
    }
}

// ============ 3x3 conv tiny cin (Rr: 3->96), fp32 ============
template<int CIN, int ACT>
__global__ __launch_bounds__(256) void conv3x3_small_kernel(
    const float* __restrict__ in, const float* __restrict__ w,
    const float* __restrict__ bias, float* __restrict__ out)
{
    const int p = blockIdx.x*256+threadIdx.x;
    const int oc = blockIdx.y;
    const int b = blockIdx.z;
    const int y = p>>7, x = p&127;
    const float* ib = in + (size_t)b*CIN*HWsz;
    float acc = bias[oc];
#pragma unroll
    for(int ci=0;ci<CIN;ci++){
        const float* wp = w + ((size_t)oc*CIN+ci)*9;
        const float* ip = ib + (size_t)ci*HWsz;
#pragma unroll
        for(int dy=0;dy<3;dy++){
            int gy=y+dy-1;
            if((unsigned)gy<128u){
#pragma unroll
                for(int dx=0;dx<3;dx++){
                    int gx=x+dx-1;
                    if((unsigned)gx<128u) acc += ip[gy*Wd+gx]*wp[dy*3+dx];
                }
            }
        }
    }
    if(ACT) acc = gelu_f(acc);
    out[((size_t)b*96+oc)*HWsz + p] = acc;
}

// ============ depthwise 3x3 over NHWC bf16; k-half -> fp32 NCHW, v-half -> bf16 NHWC ============
__global__ __launch_bounds__(256) void dw_nhwc_kernel(
    const ushortT* __restrict__ inh, const float* __restrict__ w,
    float* __restrict__ kout, ushortT* __restrict__ vouth)
{
    const int p = blockIdx.x*256+threadIdx.x;
    const int c0 = blockIdx.y*8;
    const int b = blockIdx.z;
    const int y=p>>7, x=p&127;
    float lw[72];
#pragma unroll
    for (int i=0;i<8;i++)
#pragma unroll
        for (int t=0;t<9;t++) lw[i*9+t] = w[(size_t)(c0+i)*9 + t];
    const ushortT* ib = inh + (size_t)b*HWsz*192;
    float acc[8];
#pragma unroll
    for (int i=0;i<8;i++) acc[i]=0.f;
#pragma unroll
    for(int dy=0;dy<3;dy++){
        int gy=y+dy-1;
        if((unsigned)gy<128u){
#pragma unroll
            for(int dx=0;dx<3;dx++){
                int gx=x+dx-1;
                if((unsigned)gx<128u){
                    short8v s = *(const short8v*)(ib + (size_t)(gy*Wd+gx)*192 + c0);
#pragma unroll
                    for (int i=0;i<8;i++) acc[i] += b2f((ushortT)s[i])*lw[i*9+dy*3+dx];
                }
            }
        }
    }
    if (c0 < 96){
#pragma unroll
        for (int i=0;i<8;i++)
            kout[((size_t)b*96 + c0+i)*HWsz + p] = acc[i];
    } else {
        ushortT* op = vouth + ((size_t)b*HWsz + p)*96 + (c0-96);
        uint4 pk;
        pk.x = (uintT)f2b(acc[0]) | ((uintT)f2b(acc[1])<<16);
        pk.y = (uintT)f2b(acc[2]) | ((uintT)f2b(acc[3])<<16);
        pk.z = (uintT)f2b(acc[4]) | ((uintT)f2b(acc[5])<<16);
        pk.w = (uintT)f2b(acc[6]) | ((uintT)f2b(acc[7])<<16);
        *(uint4*)op = pk;
    }
}

// ============ row L2-norm reciprocals ============
__global__ __launch_bounds__(256) void rownorm_kernel(
    const float* __restrict__ in, float* __restrict__ inv, int cpb, int cstride)
{
    __shared__ float red[256];
    const int r = blockIdx.x;
    const int b = r / cpb, c = r % cpb;
    const float* ip = in + ((size_t)b*cstride + c)*HWsz;
    float s=0.f;
    for(int p=threadIdx.x; p<HWsz; p+=256){ float v=ip[p]; s+=v*v; }
    red[threadIdx.x]=s; __syncthreads();
    for(int st=128; st>0; st>>=1){
        if(threadIdx.x<st) red[threadIdx.x]+=red[threadIdx.x+st];
        __syncthreads();
    }
    if(threadIdx.x==0) inv[r] = 1.f/fmaxf(sqrtf(red[0]), 1e-12f);
}

// ============ QK^T partials (q=C, k=F both fp32 NCHW 96ch) ============
__global__ __launch_bounds__(576) void qk_kernel(
    const float* __restrict__ q, const float* __restrict__ k, float* __restrict__ part)
{
    const int bh = blockIdx.y, b=bh>>2, h=bh&3;
    const int tid = threadIdx.x;
    const int i = tid/24, j = tid - i*24;
    const float4* qp = (const float4*)(q + ((size_t)b*96 + h*24+i)*HWsz) + blockIdx.x*128;
    const float4* kp = (const float4*)(k + ((size_t)b*96 + h*24+j)*HWsz) + blockIdx.x*128;
    float acc=0.f;
#pragma unroll 4
    for(int t=0;t<128;t++){
        float4 a=qp[t], c=kp[t];
        acc += a.x*c.x + a.y*c.y + a.z*c.z + a.w*c.w;
    }
    part[((size_t)blockIdx.x*16 + bh)*576 + tid] = acc;
}

__global__ void qk_reduce_kernel(const float* __restrict__ part, float* __restrict__ out)
{
    int idx = blockIdx.x*256+threadIdx.x;
    if(idx < 16*576){
        float s=0.f;
        for(int c=0;c<32;c++) s += part[(size_t)c*(16*576)+idx];
        out[idx]=s;
    }
}

// ============ softmax over 24 cols (norms + temp folded) ============
__global__ __launch_bounds__(576) void softmax_kernel(
    const float* __restrict__ raw, const float* __restrict__ invq,
    const float* __restrict__ invk, const float* __restrict__ temp,
    float* __restrict__ attn)
{
    __shared__ float l[576];
    const int bh=blockIdx.x, b=bh>>2, h=bh&3;
    const int tid=threadIdx.x;
    const int i=tid/24, j=tid-i*24;
    l[tid] = raw[(size_t)bh*576+tid] * invq[b*96+h*24+i] * invk[b*96+h*24+j] * temp[h];
    __syncthreads();
    if(tid<24){
        float m=-1e30f;
#pragma unroll
        for(int jj=0;jj<24;jj++) m = fmaxf(m, l[tid*24+jj]);
        float e[24]; float s=0.f;
#pragma unroll
        for(int jj=0;jj<24;jj++){ e[jj]=__expf(l[tid*24+jj]-m); s+=e[jj]; }
        float isv = 1.f/s;
#pragma unroll
        for(int jj=0;jj<24;jj++) attn[(size_t)bh*576 + tid*24 + jj] = e[jj]*isv;
    }
}

// ============ M_b = po_w @ blockdiag(attn_b), packed to B-frag bf16 ============
__global__ __launch_bounds__(256) void mkM_kernel(
    const float* __restrict__ attn, const float* __restrict__ po_w,
    ushortT* __restrict__ Mpk)
{
    const int b = blockIdx.x;
    for (int e = threadIdx.x; e < 9216; e += 256){
        int oc = e / 96, d = e - oc*96;
        int h = d / 24, dl = d - h*24;
        const float* aw = attn + ((size_t)(b*4+h))*576 + dl;
        const float* pw = po_w + (size_t)oc*96 + h*24;
        float s = 0.f;
#pragma unroll
        for (int c=0;c<24;c++) s += pw[c]*aw[c*24];
        int ch = d>>5, kg = (d>>3)&3, j = d&7;
        Mpk[(size_t)b*9216 + ((size_t)(ch*4+kg)*96 + oc)*8 + j] = f2b(s);
    }
}

extern "C" void kernel_launch(void* const* d_in, const int* in_sizes, int n_in,
                              void* d_out, int out_size, void* d_ws, size_t ws_size,
                              hipStream_t stream)
{
    const float* x     = (const float*)d_in[0];
    const float* Lc_w1 = (const float*)d_in[1];
    const float* Lc_b1 = (const float*)d_in[2];
    const float* Lc_w2 = (const float*)d_in[3];
    const float* Lc_b2 = (const float*)d_in[4];
    const float* Rc_w1 = (const float*)d_in[5];
    const float* Rc_b1 = (const float*)d_in[6];
    const float* Rc_w2 = (const float*)d_in[7];
    const float* Rc_b2 = (const float*)d_in[8];
    const float* Lr_w  = (const float*)d_in[9];
    const float* Lr_b  = (const float*)d_in[10];
    const float* Rr_w  = (const float*)d_in[11];
    const float* Rr_b  = (const float*)d_in[12];
    const float* n1_w  = (const float*)d_in[13];
    const float* n1_b  = (const float*)d_in[14];
    const float* nL_w  = (const float*)d_in[15];
    const float* nL_b  = (const float*)d_in[16];
    const float* n2_w  = (const float*)d_in[17];
    const float* n2_b  = (const float*)d_in[18];
    const float* temp  = (const float*)d_in[19];
    const float* q_w   = (const float*)d_in[20];
    const float* qd_w  = (const float*)d_in[21];
    const float* kv_w  = (const float*)d_in[22];
    const float* kvd_w = (const float*)d_in[23];
    const float* po_w  = (const float*)d_in[24];
    const float* pi_w  = (const float*)d_in[25];
    const float* fdw_w = (const float*)d_in[26];
    const float* fpo_w = (const float*)d_in[27];

    char* base = (char*)d_ws;
    // bf16 NHWC pools (time-disjoint overlays)
    ushortT* xh   = (ushortT*)(base + 0);             // P1: xh(12.6M) -> f0h(33.5M)
    ushortT* f0h  = (ushortT*)(base + 0);
    ushortT* Lh   = (ushortT*)(base + 33554432);      // P2: Lh -> kv0h -> f1h
    ushortT* kv0h = (ushortT*)(base + 33554432);
    ushortT* f1h  = (ushortT*)(base + 33554432);
    ushortT* Rh   = (ushortT*)(base + 67108864);      // P3: Rh -> vh -> x2nh
    ushortT* vh   = (ushortT*)(base + 67108864);
    ushortT* x2nh = (ushortT*)(base + 67108864);
    ushortT* illh = (ushortT*)(base + 79691776);      // P4
    ushortT* xnh  = (ushortT*)(base + 92274688);      // P5
    ushortT* q0h  = (ushortT*)(base + 104857600);     // P6
    float*   C    = (float*)(base + 117440512);       // q fp32 -> x1
    float*   x1   = C;
    float*   F    = (float*)(base + 142606336);       // k fp32
    float*   Bb   = (float*)(base + 167772160);       // R_rein fp32
    // small region
    char* smb = base + 192937984;
    ushortT* wpkL = (ushortT*)smb;                smb += 165888;
    ushortT* wpkR = (ushortT*)smb;                smb += 165888;
    ushortT* wpkQ = (ushortT*)smb;                smb += 165888;
    ushortT* wpkF = (ushortT*)smb;                smb += 1179648;
    ushortT* wq0  = (ushortT*)smb;                smb += 18432;
    ushortT* wkv  = (ushortT*)smb;                smb += 36864;
    ushortT* wpi  = (ushortT*)smb;                smb += 49152;
    ushortT* wfpo = (ushortT*)smb;                smb += 49152;
    ushortT* Mpk  = (ushortT*)smb;                smb += 73728;
    float* invq = (float*)smb;                    smb += 1536;
    float* invk = (float*)smb;                    smb += 1536;
    float* part = (float*)smb;                    smb += 1179648;
    float* araw = (float*)smb;                    smb += 36864;
    float* attn = (float*)smb;                    smb += 36864;

    float* out_x = (float*)d_out;
    float* out_L = out_x + (size_t)4*96*HWsz;
    float* out_R = out_L + (size_t)4*HWsz;

    dim3 blk(256);

    // ---- weight packing + input convert ----
    hipLaunchKernelGGL(pack_w_kernel,  dim3(324),  blk, 0, stream, Lc_w1, wpkL, 96, 96, 48, 3, 82944);
    hipLaunchKernelGGL(pack_w_kernel,  dim3(324),  blk, 0, stream, Rc_w1, wpkR, 96, 96, 48, 3, 82944);
    hipLaunchKernelGGL(pack_w_kernel,  dim3(324),  blk, 0, stream, qd_w,  wpkQ, 96, 96, 48, 3, 82944);
    hipLaunchKernelGGL(pack_w_kernel,  dim3(2304), blk, 0, stream, fdw_w, wpkF, 255, 255, 64, 8, 589824);
    hipLaunchKernelGGL(pack_w1_kernel, dim3(36),   blk, 0, stream, q_w,  wq0,  96, 96, 96, 3, 9216);
    hipLaunchKernelGGL(pack_w1_kernel, dim3(72),   blk, 0, stream, kv_w, wkv, 192, 96, 96, 3, 18432);
    hipLaunchKernelGGL(pack_w1_kernel, dim3(96),   blk, 0, stream, pi_w, wpi, 255, 96, 64, 3, 24576);
    hipLaunchKernelGGL(pack_w1_kernel, dim3(96),   blk, 0, stream, fpo_w, wfpo, 96, 255, 96, 8, 24576);
    hipLaunchKernelGGL(tonhwc_kernel,  dim3(64,4), blk, 0, stream, x, xh);

    // ---- Retinex heads ----
    hipLaunchKernelGGL((conv3x3_mfma<3,3,1,1>), dim3(64,2,4), blk, 0, stream, xh, wpkL, Lc_b1, (void*)Lh, 96, 96);
    hipLaunchKernelGGL((head1x1_kernel<1>), dim3(64,4), blk, 0, stream, Lh, Lc_w2, Lc_b2, out_L);
    hipLaunchKernelGGL((conv3x3_mfma<3,3,1,1>), dim3(64,2,4), blk, 0, stream, xh, wpkR, Rc_b1, (void*)Rh, 96, 96);
    hipLaunchKernelGGL((head1x1_kernel<3>), dim3(64,4), blk, 0, stream, Rh, Rc_w2, Rc_b2, out_R);
    hipLaunchKernelGGL(lrein_ln_kernel, dim3(64,4), blk, 0, stream, out_L, Lr_w, Lr_b, nL_w, nL_b, illh);
    hipLaunchKernelGGL((conv3x3_small_kernel<3,0>), dim3(64,96,4), blk, 0, stream, out_R, Rr_w, Rr_b, Bb);

    // ---- n1 norm ----
    hipLaunchKernelGGL(ln_n2n_kernel, dim3(64,4), blk, 0, stream, x, n1_w, n1_b, xnh);

    // ---- q path ----
    hipLaunchKernelGGL((gemm1x1_mfma<6,3,0,1>), dim3(64,1,4), blk, 0, stream, illh, wq0, 0, nullptr, nullptr, (void*)q0h, 96, 96);
    hipLaunchKernelGGL((conv3x3_mfma<3,3,0,0>), dim3(64,2,4), blk, 0, stream, q0h, wpkQ, nullptr, (void*)C, 96, 0);
    // ---- kv path ----
    hipLaunchKernelGGL((gemm1x1_mfma<6,3,0,1>), dim3(64,2,4), blk, 0, stream, xnh, wkv, 0, nullptr, nullptr, (void*)kv0h, 192, 192);
    hipLaunchKernelGGL(dw_nhwc_kernel, dim3(64,24,4), blk, 0, stream, kv0h, kvd_w, F, vh);

    // ---- attention ----
    hipLaunchKernelGGL(rownorm_kernel, dim3(384), blk, 0, stream, C, invq, 96, 96);
    hipLaunchKernelGGL(rownorm_kernel, dim3(384), blk, 0, stream, F, invk, 96, 96);
    hipLaunchKernelGGL(qk_kernel, dim3(32,16), dim3(576), 0, stream, C, F, part);
    hipLaunchKernelGGL(qk_reduce_kernel, dim3(36), blk, 0, stream, part, araw);
    hipLaunchKernelGGL(softmax_kernel, dim3(16), dim3(576), 0, stream, araw, invq, invk, temp, attn);
    hipLaunchKernelGGL(mkM_kernel, dim3(4), blk, 0, stream, attn, po_w, Mpk);
    // fused pv+po: x1 = x + (M_b @ v)
    hipLaunchKernelGGL((gemm1x1_mfma<6,3,1,0>), dim3(64,1,4), blk, 0, stream, vh, Mpk, 9216, x, nullptr, (void*)x1, 96, 0);

    // ---- FFN ----
    hipLaunchKernelGGL(ln_n2n_kernel, dim3(64,4), blk, 0, stream, x1, n2_w, n2_b, x2nh);
    hipLaunchKernelGGL((gemm1x1_mfma<4,3,0,1>), dim3(64,4,4), blk, 0, stream, x2nh, wpi, 0, nullptr, nullptr, (void*)f0h, 255, 256);
    hipLaunchKernelGGL((conv3x3_mfma<4,8,1,1>), dim3(64,4,4), blk, 0, stream, f0h, wpkF, nullptr, (void*)f1h, 255, 256);
    hipLaunchKernelGGL((gemm1x1_mfma<6,8,2,0>), dim3(64,1,4), blk, 0, stream, f1h, wfpo, 0, x1, Bb, (void*)out_x, 96, 0);
}

// Round 4
// 508.288 us; speedup vs baseline: 10.4265x; 1.1904x over previous
//
#include <hip/hip_runtime.h>

#define HWsz 16384
#define Wd 128

typedef unsigned short ushortT;
typedef unsigned int uintT;
typedef __attribute__((ext_vector_type(8))) short short8v;
typedef __attribute__((ext_vector_type(4))) float f32x4;
typedef __attribute__((ext_vector_type(16))) float f32x16;
typedef __attribute__((ext_vector_type(4))) unsigned short ushort4v;

__device__ __forceinline__ float gelu_f(float x){
    return 0.5f * x * (1.0f + erff(x * 0.70710678118654752f));
}
__device__ __forceinline__ ushortT f2b(float f){
    union { float f; uintT u; } v; v.f = f;
    uintT r = v.u + 0x7FFFu + ((v.u >> 16) & 1u);   // RNE
    return (ushortT)(r >> 16);
}
__device__ __forceinline__ float b2f(ushortT u){
    union { uintT u; float f; } v; v.u = ((uintT)u) << 16; return v.f;
}

// ============ merged weight packing ============
__device__ __forceinline__ void pack3_one(int e, const float* __restrict__ w,
    ushortT* __restrict__ outp, int cout, int cin, int BN, int NCH)
{
    int j = e & 7; int r = e >> 3;
    int ocl = r % BN; r /= BN;
    int kg  = r & 3;  r >>= 2;
    int tap = r % 9;  r /= 9;
    int ch  = r % NCH;
    int nt  = r / NCH;
    int ci = ch*32 + kg*8 + j;
    int oc = nt*BN + ocl;
    float v = (oc < cout && ci < cin) ? w[((size_t)oc*cin + ci)*9 + tap] : 0.f;
    outp[e] = f2b(v);
}
__device__ __forceinline__ void pack1_one(int e, const float* __restrict__ w,
    ushortT* __restrict__ outp, int cout, int cin, int BN, int NCH)
{
    int j = e & 7; int r = e >> 3;
    int ocl = r % BN; r /= BN;
    int kg  = r & 3;  r >>= 2;
    int ch  = r % NCH;
    int nt  = r / NCH;
    int ci = ch*32 + kg*8 + j;
    int oc = nt*BN + ocl;
    float v = (oc < cout && ci < cin) ? w[(size_t)oc*cin + ci] : 0.f;
    outp[e] = f2b(v);
}
__global__ __launch_bounds__(256) void pack_all_kernel(
    const float* Lc, const float* Rc, const float* Qd, const float* Fd,
    const float* Q1, const float* KV1, const float* PI1, const float* FPO1,
    ushortT* dL, ushortT* dR, ushortT* dQ, ushortT* dF,
    ushortT* dq0, ushortT* dkv, ushortT* dpi, ushortT* dfpo)
{
    int e = blockIdx.x*256 + threadIdx.x;
    if      (e < 82944)  pack3_one(e,        Lc, dL, 96, 96, 48, 3);
    else if (e < 165888) pack3_one(e-82944,  Rc, dR, 96, 96, 48, 3);
    else if (e < 248832) pack3_one(e-165888, Qd, dQ, 96, 96, 32, 3);
    else if (e < 838656) pack3_one(e-248832, Fd, dF, 255,255, 64, 8);
    else if (e < 847872) pack1_one(e-838656, Q1, dq0, 96, 96, 96, 3);
    else if (e < 866304) pack1_one(e-847872, KV1,dkv, 192,96, 96, 3);
    else if (e < 890880) pack1_one(e-866304, PI1,dpi, 255,96, 64, 3);
    else if (e < 915456) pack1_one(e-890880, FPO1,dfpo,96,255, 96, 8);
}

// ============ x (NCHW fp32, 96ch) -> NHWC bf16 ============
__global__ __launch_bounds__(256) void tonhwc_kernel(
    const float* __restrict__ in, ushortT* __restrict__ outp)
{
    const int p = blockIdx.x*256 + threadIdx.x;
    const int b = blockIdx.y;
    const float* ip = in + (size_t)b*96*HWsz + p;
    ushortT* op = outp + ((size_t)b*HWsz + p)*96;
#pragma unroll
    for (int g=0; g<12; g++){
        float v[8];
#pragma unroll
        for (int c=0;c<8;c++) v[c] = ip[(size_t)(g*8+c)*HWsz];
        uint4 pk;
        pk.x = (uintT)f2b(v[0]) | ((uintT)f2b(v[1])<<16);
        pk.y = (uintT)f2b(v[2]) | ((uintT)f2b(v[3])<<16);
        pk.z = (uintT)f2b(v[4]) | ((uintT)f2b(v[5])<<16);
        pk.w = (uintT)f2b(v[6]) | ((uintT)f2b(v[7])<<16);
        *(uint4*)(op + g*8) = pk;
    }
}

// ============ MFMA implicit-GEMM 3x3 conv; B-frags straight from L2 ============
// OMODE: 0 fp32 NCHW, 1 bf16 NHWC[ocpad], 2 bf16 NCHW.
// NSPLIT>0: blockIdx.y >= NSPLIT uses the second weight/bias/out set.
template<int NG, int NCH, int ACT, int OMODE, int NSPLIT>
__global__ __launch_bounds__(256,4) void conv3x3_mfma(
    const ushortT* __restrict__ inh,
    const ushortT* __restrict__ wpk1, const ushortT* __restrict__ wpk2,
    const float* __restrict__ bias1, const float* __restrict__ bias2,
    void* __restrict__ out1, void* __restrict__ out2,
    int cout, int ocpad)
{
    constexpr int BN = NG*16;
    constexpr int Cpad = NCH*32;
    __shared__ __align__(16) ushortT As[4*324*8];

    const int tid = threadIdx.x;
    const int l   = tid & 63;
    const int wv  = tid >> 6;
    const int l15 = l & 15;
    const int kg  = l >> 4;
    const int tix = blockIdx.x & 7, tiy = blockIdx.x >> 3;
    int nt = blockIdx.y;
    const int b   = blockIdx.z;

    const ushortT* wpk = wpk1; const float* bias = bias1; void* outv = out1;
    if (NSPLIT > 0 && nt >= NSPLIT){ nt -= NSPLIT; wpk = wpk2; bias = bias2; outv = out2; }

    f32x4 acc[4][NG];
#pragma unroll
    for (int m=0;m<4;m++)
#pragma unroll
        for (int n=0;n<NG;n++) acc[m][n] = (f32x4){0.f,0.f,0.f,0.f};

    const ushortT* inb = inh + (size_t)b*HWsz*Cpad;

    for (int ch=0; ch<NCH; ch++){
        __syncthreads();
#pragma unroll
        for (int g=0; g<4; g++){
            for (int p=tid; p<324; p+=256){
                int hy = p/18, hx = p - hy*18;
                int gy = tiy*16 + hy - 1, gx = tix*16 + hx - 1;
                uint4 v; v.x=0u; v.y=0u; v.z=0u; v.w=0u;
                if ((unsigned)gy < 128u && (unsigned)gx < 128u)
                    v = *(const uint4*)(inb + (size_t)(gy*Wd+gx)*Cpad + ch*32 + g*8);
                *(uint4*)(As + (g*324+p)*8) = v;
            }
        }
        __syncthreads();
        const ushortT* wch = wpk + (size_t)(nt*NCH + ch)*(9*4*BN*8);
#pragma unroll
        for (int tp=0; tp<9; tp++){
            const int dy = tp/3, dx = tp - dy*3;
            short8v a[4], bf[NG];
#pragma unroll
            for (int mg=0; mg<4; mg++){
                int p = (wv*4 + mg + dy)*18 + l15 + dx;
                a[mg] = *(const short8v*)(As + (kg*324 + p)*8);
            }
#pragma unroll
            for (int n=0;n<NG;n++)
                bf[n] = *(const short8v*)(wch + ((size_t)(tp*4 + kg)*BN + n*16 + l15)*8);
#pragma unroll
            for (int mg=0;mg<4;mg++)
#pragma unroll
                for (int n=0;n<NG;n++)
                    acc[mg][n] = __builtin_amdgcn_mfma_f32_16x16x32_bf16(a[mg], bf[n], acc[mg][n], 0,0,0);
        }
    }
    // D: col=lane&15 (oc), row=(lane>>4)*4+j (pixel): gy=tiy*16+wv*4+mg, gx=tix*16+kg*4+j
    if (OMODE == 0){
        float* out = (float*)outv;
#pragma unroll
        for (int n=0;n<NG;n++){
            int oc = nt*BN + n*16 + l15;
            if (oc < cout){
                float bs = bias ? bias[oc] : 0.f;
#pragma unroll
                for (int mg=0;mg<4;mg++){
                    int gy = tiy*16 + wv*4 + mg;
                    int gx = tix*16 + kg*4;
                    float4 r;
                    r.x = acc[mg][n][0] + bs; r.y = acc[mg][n][1] + bs;
                    r.z = acc[mg][n][2] + bs; r.w = acc[mg][n][3] + bs;
                    if (ACT){ r.x=gelu_f(r.x); r.y=gelu_f(r.y); r.z=gelu_f(r.z); r.w=gelu_f(r.w); }
                    *(float4*)(out + ((size_t)b*cout + oc)*HWsz + gy*Wd + gx) = r;
                }
            }
        }
    } else if (OMODE == 1){
        ushortT* out = (ushortT*)outv;
#pragma unroll
        for (int n=0;n<NG;n++){
            int oc = nt*BN + n*16 + l15;
            float bs = (bias && oc < cout) ? bias[oc] : 0.f;
#pragma unroll
            for (int mg=0;mg<4;mg++){
                int gy = tiy*16 + wv*4 + mg;
                int gx = tix*16 + kg*4;
#pragma unroll
                for (int j=0;j<4;j++){
                    float r = 0.f;
                    if (oc < cout){
                        r = acc[mg][n][j] + bs;
                        if (ACT) r = gelu_f(r);
                    }
                    out[((size_t)b*HWsz + gy*Wd + gx + j)*ocpad + oc] = f2b(r);
                }
            }
        }
    } else {
        ushortT* out = (ushortT*)outv;
#pragma unroll
        for (int n=0;n<NG;n++){
            int oc = nt*BN + n*16 + l15;
            if (oc < cout){
                float bs = bias ? bias[oc] : 0.f;
#pragma unroll
                for (int mg=0;mg<4;mg++){
                    int gy = tiy*16 + wv*4 + mg;
                    int gx = tix*16 + kg*4;
                    ushort4v pk;
#pragma unroll
                    for (int j=0;j<4;j++){
                        float r = acc[mg][n][j] + bs;
                        if (ACT) r = gelu_f(r);
                        pk[j] = f2b(r);
                    }
                    *(ushort4v*)(out + ((size_t)b*cout + oc)*HWsz + gy*Wd + gx) = pk;
                }
            }
        }
    }
}

// ============ MFMA 1x1 GEMM (no LDS/barriers) ============
// RES: 0 none; 1 +res1(fp32); 2 +res1(fp32)+res2b(bf16 NCHW). OMODE: 0 fp32 NCHW, 1 bf16 NHWC.
template<int NG, int NCH, int RES, int OMODE>
__global__ __launch_bounds__(256) void gemm1x1_mfma(
    const ushortT* __restrict__ inh, const ushortT* __restrict__ wpk, int wstride_z,
    const float* __restrict__ res1, const ushortT* __restrict__ res2b,
    void* __restrict__ outv, int cout, int ocpad)
{
    constexpr int BN = NG*16;
    constexpr int Cpad = NCH*32;
    const int tid = threadIdx.x;
    const int l = tid & 63, wv = tid >> 6, l15 = l & 15, kg = l >> 4;
    const int nt = blockIdx.y, b = blockIdx.z;
    const int p0 = blockIdx.x*256 + wv*64;
    const ushortT* inb = inh + (size_t)b*HWsz*Cpad;
    const ushortT* wp  = wpk + (size_t)b*wstride_z;

    f32x4 acc[4][NG];
#pragma unroll
    for (int m=0;m<4;m++)
#pragma unroll
        for (int n=0;n<NG;n++) acc[m][n] = (f32x4){0.f,0.f,0.f,0.f};

#pragma unroll
    for (int ch=0; ch<NCH; ch++){
        short8v a[4], bw[NG];
#pragma unroll
        for (int mg=0; mg<4; mg++)
            a[mg] = *(const short8v*)(inb + (size_t)(p0 + mg*16 + l15)*Cpad + ch*32 + kg*8);
#pragma unroll
        for (int n=0;n<NG;n++)
            bw[n] = *(const short8v*)(wp + (((size_t)(nt*NCH + ch)*4 + kg)*BN + n*16 + l15)*8);
#pragma unroll
        for (int mg=0;mg<4;mg++)
#pragma unroll
            for (int n=0;n<NG;n++)
                acc[mg][n] = __builtin_amdgcn_mfma_f32_16x16x32_bf16(a[mg], bw[n], acc[mg][n], 0,0,0);
    }
    if (OMODE == 0){
        float* out = (float*)outv;
#pragma unroll
        for (int n=0;n<NG;n++){
            int oc = nt*BN + n*16 + l15;
            if (oc < cout){
#pragma unroll
                for (int mg=0;mg<4;mg++){
                    int pix = p0 + mg*16 + kg*4;
                    size_t idx = ((size_t)b*cout + oc)*HWsz + pix;
                    float4 r;
                    r.x = acc[mg][n][0]; r.y = acc[mg][n][1];
                    r.z = acc[mg][n][2]; r.w = acc[mg][n][3];
                    if (RES>=1){ float4 q = *(const float4*)(res1+idx); r.x+=q.x;r.y+=q.y;r.z+=q.z;r.w+=q.w; }
                    if (RES>=2){
                        ushort4v q = *(const ushort4v*)(res2b+idx);
                        r.x+=b2f(q[0]); r.y+=b2f(q[1]); r.z+=b2f(q[2]); r.w+=b2f(q[3]);
                    }
                    *(float4*)(out + idx) = r;
                }
            }
        }
    } else {
        ushortT* out = (ushortT*)outv;
#pragma unroll
        for (int n=0;n<NG;n++){
            int oc = nt*BN + n*16 + l15;
#pragma unroll
            for (int mg=0;mg<4;mg++){
                int pix = p0 + mg*16 + kg*4;
#pragma unroll
                for (int j=0;j<4;j++){
                    float r = (oc < cout) ? acc[mg][n][j] : 0.f;
                    out[((size_t)b*HWsz + pix + j)*ocpad + oc] = f2b(r);
                }
            }
        }
    }
}

// ============ head 1x1 (96 -> NOUT), NHWC bf16 in, NCHW fp32 out ============
template<int NOUT>
__global__ __launch_bounds__(256) void head1x1_kernel(
    const ushortT* __restrict__ inh, const float* __restrict__ w,
    const float* __restrict__ bias, float* __restrict__ out)
{
    __shared__ float lw[NOUT*96];
    const int tid = threadIdx.x;
    for (int t=tid; t<NOUT*96; t+=256) lw[t] = w[t];
    __syncthreads();
    const int p = blockIdx.x*256 + tid;
    const int b = blockIdx.y;
    const ushortT* ip = inh + ((size_t)b*HWsz + p)*96;
    float v[96];
#pragma unroll
    for (int g=0; g<12; g++){
        short8v s = *(const short8v*)(ip + g*8);
#pragma unroll
        for (int i=0;i<8;i++) v[g*8+i] = b2f((ushortT)s[i]);
    }
#pragma unroll
    for (int oc=0; oc<NOUT; oc++){
        float acc = bias[oc];
#pragma unroll
        for (int c=0;c<96;c++) acc += v[c]*lw[oc*96+c];
        out[((size_t)b*NOUT + oc)*HWsz + p] = acc;
    }
}

// ============ fused: Lr conv3x3(1->96)+bias+GELU + LayerNorm(nL) -> illh bf16 NHWC ============
__global__ __launch_bounds__(256) void lrein_ln_kernel(
    const float* __restrict__ L, const float* __restrict__ w,
    const float* __restrict__ bias, const float* __restrict__ lnw,
    const float* __restrict__ lnb, ushortT* __restrict__ outh)
{
    __shared__ float sw[864], sb[96], sn1[96], sn2[96];
    const int tid = threadIdx.x;
    for (int t=tid; t<864; t+=256) sw[t] = w[t];
    if (tid < 96){ sb[tid]=bias[tid]; sn1[tid]=lnw[tid]; sn2[tid]=lnb[tid]; }
    __syncthreads();
    const int p = blockIdx.x*256 + tid;
    const int b = blockIdx.y;
    const int y = p>>7, x = p&127;
    const float* ib = L + (size_t)b*HWsz;
    float win[9];
#pragma unroll
    for (int dy=0;dy<3;dy++)
#pragma unroll
        for (int dx=0;dx<3;dx++){
            int gy=y+dy-1, gx=x+dx-1;
            win[dy*3+dx] = ((unsigned)gy<128u && (unsigned)gx<128u) ? ib[gy*Wd+gx] : 0.f;
        }
    float v[96]; float s=0.f;
#pragma unroll
    for (int c=0;c<96;c++){
        float a = sb[c];
#pragma unroll
        for (int t=0;t<9;t++) a += win[t]*sw[c*9+t];
        a = gelu_f(a);
        v[c]=a; s+=a;
    }
    const float mu = s*(1.f/96.f);
    float s2=0.f;
#pragma unroll
    for (int c=0;c<96;c++){ float d=v[c]-mu; s2+=d*d; }
    const float inv = 1.f/sqrtf(s2*(1.f/96.f)+1e-5f);
    ushortT* op = outh + ((size_t)b*HWsz + p)*96;
#pragma unroll
    for (int g=0; g<12; g++){
        uint4 pk; uintT w4[4];
#pragma unroll
        for (int i=0;i<4;i++){
            float r0 = (v[g*8+2*i]-mu)*inv*sn1[g*8+2*i]+sn2[g*8+2*i];
            float r1 = (v[g*8+2*i+1]-mu)*inv*sn1[g*8+2*i+1]+sn2[g*8+2*i+1];
            w4[i] = (uintT)f2b(r0) | ((uintT)f2b(r1)<<16);
        }
        pk.x=w4[0]; pk.y=w4[1]; pk.z=w4[2]; pk.w=w4[3];
        *(uint4*)(op + g*8) = pk;
    }
}

// ============ LayerNorm: NCHW fp32 -> NHWC bf16 ============
__global__ __launch_bounds__(256) void ln_n2n_kernel(
    const float* __restrict__ in, const float* __restrict__ w,
    const float* __restrict__ bias, ushortT* __restrict__ outh)
{
    const int p = blockIdx.x*256+threadIdx.x;
    const int b = blockIdx.y;
    const float* ip = in + (size_t)b*96*HWsz + p;
    float v[96]; float s=0.f;
#pragma unroll
    for(int c=0;c<96;c++){ v[c]=ip[(size_t)c*HWsz]; s+=v[c]; }
    const float mu = s*(1.f/96.f);
    float s2=0.f;
#pragma unroll
    for(int c=0;c<96;c++){ float d=v[c]-mu; s2+=d*d; }
    const float inv = 1.f/sqrtf(s2*(1.f/96.f)+1e-5f);
    ushortT* op = outh + ((size_t)b*HWsz + p)*96;
#pragma unroll
    for (int g=0; g<12; g++){
        uint4 pk; uintT w4[4];
#pragma unroll
        for (int i=0;i<4;i++){
            float r0 = (v[g*8+2*i]-mu)*inv*w[g*8+2*i]+bias[g*8+2*i];
            float r1 = (v[g*8+2*i+1]-mu)*inv*w[g*8+2*i+1]+bias[g*8+2*i+1];
            w4[i] = (uintT)f2b(r0) | ((uintT)f2b(r1)<<16);
        }
        pk.x=w4[0]; pk.y=w4[1]; pk.z=w4[2]; pk.w=w4[3];
        *(uint4*)(op + g*8) = pk;
    }
}

// ============ 3x3 conv tiny cin (Rr: 3->96) -> bf16 NCHW ============
template<int CIN, int ACT>
__global__ __launch_bounds__(256) void conv3x3_small_kernel(
    const float* __restrict__ in, const float* __restrict__ w,
    const float* __restrict__ bias, ushortT* __restrict__ out)
{
    const int p = blockIdx.x*256+threadIdx.x;
    const int oc = blockIdx.y;
    const int b = blockIdx.z;
    const int y = p>>7, x = p&127;
    const float* ib = in + (size_t)b*CIN*HWsz;
    float acc = bias[oc];
#pragma unroll
    for(int ci=0;ci<CIN;ci++){
        const float* wp = w + ((size_t)oc*CIN+ci)*9;
        const float* ip = ib + (size_t)ci*HWsz;
#pragma unroll
        for(int dy=0;dy<3;dy++){
            int gy=y+dy-1;
            if((unsigned)gy<128u){
#pragma unroll
                for(int dx=0;dx<3;dx++){
                    int gx=x+dx-1;
                    if((unsigned)gx<128u) acc += ip[gy*Wd+gx]*wp[dy*3+dx];
                }
            }
        }
    }
    if(ACT) acc = gelu_f(acc);
    out[((size_t)b*96+oc)*HWsz + p] = f2b(acc);
}

// ============ depthwise 3x3 NHWC bf16; k-half -> bf16 NCHW, v-half -> bf16 NHWC ============
__global__ __launch_bounds__(256) void dw_nhwc_kernel(
    const ushortT* __restrict__ inh, const float* __restrict__ w,
    ushortT* __restrict__ kout, ushortT* __restrict__ vouth)
{
    const int p = blockIdx.x*256+threadIdx.x;
    const int c0 = blockIdx.y*8;
    const int b = blockIdx.z;
    const int y=p>>7, x=p&127;
    float lw[72];
#pragma unroll
    for (int i=0;i<8;i++)
#pragma unroll
        for (int t=0;t<9;t++) lw[i*9+t] = w[(size_t)(c0+i)*9 + t];
    const ushortT* ib = inh + (size_t)b*HWsz*192;
    float acc[8];
#pragma unroll
    for (int i=0;i<8;i++) acc[i]=0.f;
#pragma unroll
    for(int dy=0;dy<3;dy++){
        int gy=y+dy-1;
        if((unsigned)gy<128u){
#pragma unroll
            for(int dx=0;dx<3;dx++){
                int gx=x+dx-1;
                if((unsigned)gx<128u){
                    short8v s = *(const short8v*)(ib + (size_t)(gy*Wd+gx)*192 + c0);
#pragma unroll
                    for (int i=0;i<8;i++) acc[i] += b2f((ushortT)s[i])*lw[i*9+dy*3+dx];
                }
            }
        }
    }
    if (c0 < 96){
#pragma unroll
        for (int i=0;i<8;i++)
            kout[((size_t)b*96 + c0+i)*HWsz + p] = f2b(acc[i]);
    } else {
        ushortT* op = vouth + ((size_t)b*HWsz + p)*96 + (c0-96);
        uint4 pk;
        pk.x = (uintT)f2b(acc[0]) | ((uintT)f2b(acc[1])<<16);
        pk.y = (uintT)f2b(acc[2]) | ((uintT)f2b(acc[3])<<16);
        pk.z = (uintT)f2b(acc[4]) | ((uintT)f2b(acc[5])<<16);
        pk.w = (uintT)f2b(acc[6]) | ((uintT)f2b(acc[7])<<16);
        *(uint4*)op = pk;
    }
}

// ============ row L2-norm reciprocals for q(bf16 NCHW) and k(bf16 NCHW) ============
__global__ __launch_bounds__(256) void rownorm_bf16_kernel(
    const ushortT* __restrict__ qb, const ushortT* __restrict__ kb,
    float* __restrict__ invqk)
{
    __shared__ float red[256];
    const int r = blockIdx.x;       // 0..767
    const ushortT* ip = (r < 384) ? (qb + (size_t)r*HWsz) : (kb + (size_t)(r-384)*HWsz);
    float s=0.f;
    const ushortT* tp = ip + threadIdx.x*64;
#pragma unroll
    for (int g=0; g<8; g++){
        short8v v = *(const short8v*)(tp + g*8);
#pragma unroll
        for (int i=0;i<8;i++){ float f = b2f((ushortT)v[i]); s += f*f; }
    }
    red[threadIdx.x]=s; __syncthreads();
    for(int st=128; st>0; st>>=1){
        if(threadIdx.x<st) red[threadIdx.x]+=red[threadIdx.x+st];
        __syncthreads();
    }
    if(threadIdx.x==0) invqk[r] = 1.f/fmaxf(sqrtf(red[0]), 1e-12f);
}

// ============ QK^T Gram via MFMA 32x32x16 (partials over 32 pixel-chunks) ============
__global__ __launch_bounds__(256) void qk_mfma_kernel(
    const ushortT* __restrict__ qb, const ushortT* __restrict__ kb,
    float* __restrict__ part)
{
    const int tid = threadIdx.x;
    const int l = tid & 63, wv = tid >> 6;
    const int chunk = blockIdx.x*4 + wv;          // 0..31 (512 px each)
    const int bh = blockIdx.y, b = bh>>2, h = bh&3;
    const int ch = min(l & 31, 23);
    const int kh = (l >> 5)*8;
    const ushortT* qp = qb + ((size_t)b*96 + h*24 + ch)*HWsz + chunk*512 + kh;
    const ushortT* kp = kb + ((size_t)b*96 + h*24 + ch)*HWsz + chunk*512 + kh;
    f32x16 acc;
#pragma unroll
    for (int r=0;r<16;r++) acc[r]=0.f;
    for (int ks=0; ks<32; ks++){
        short8v a  = *(const short8v*)(qp + ks*16);
        short8v bb = *(const short8v*)(kp + ks*16);
        acc = __builtin_amdgcn_mfma_f32_32x32x16_bf16(a, bb, acc, 0,0,0);
    }
    float* op = part + ((size_t)chunk*16 + bh)*1024;
    const int col = l & 31;
#pragma unroll
    for (int r=0;r<16;r++){
        int row = (r&3) + 8*(r>>2) + 4*(l>>5);
        op[row*32 + col] = acc[r];
    }
}

__global__ void qk_reduce_kernel(const float* __restrict__ part, float* __restrict__ out)
{
    int idx = blockIdx.x*256+threadIdx.x;      // 16*1024
    float s=0.f;
    for(int c=0;c<32;c++) s += part[(size_t)c*16384 + idx];
    out[idx]=s;
}

// ============ softmax over 24 cols (norms + temp folded) ============
__global__ __launch_bounds__(576) void softmax_kernel(
    const float* __restrict__ raw, const float* __restrict__ invq,
    const float* __restrict__ invk, const float* __restrict__ temp,
    float* __restrict__ attn)
{
    __shared__ float l[576];
    const int bh=blockIdx.x, b=bh>>2, h=bh&3;
    const int tid=threadIdx.x;
    const int i=tid/24, j=tid-i*24;
    l[tid] = raw[(size_t)bh*1024 + i*32 + j] * invq[b*96+h*24+i] * invk[b*96+h*24+j] * temp[h];
    __syncthreads();
    if(tid<24){
        float m=-1e30f;
#pragma unroll
        for(int jj=0;jj<24;jj++) m = fmaxf(m, l[tid*24+jj]);
        float e[24]; float s=0.f;
#pragma unroll
        for(int jj=0;jj<24;jj++){ e[jj]=__expf(l[tid*24+jj]-m); s+=e[jj]; }
        float isv = 1.f/s;
#pragma unroll
        for(int jj=0;jj<24;jj++) attn[(size_t)bh*576 + tid*24 + jj] = e[jj]*isv;
    }
}

// ============ M_b = po_w @ blockdiag(attn_b), packed to B-frag bf16 ============
__global__ __launch_bounds__(256) void mkM_kernel(
    const float* __restrict__ attn, const float* __restrict__ po_w,
    ushortT* __restrict__ Mpk)
{
    const int b = blockIdx.x;
    for (int e = threadIdx.x; e < 9216; e += 256){
        int oc = e / 96, d = e - oc*96;
        int h = d / 24, dl = d - h*24;
        const float* aw = attn + ((size_t)(b*4+h))*576 + dl;
        const float* pw = po_w + (size_t)oc*96 + h*24;
        float s = 0.f;
#pragma unroll
        for (int c=0;c<24;c++) s += pw[c]*aw[c*24];
        int ch = d>>5, kg = (d>>3)&3, j = d&7;
        Mpk[(size_t)b*9216 + ((size_t)(ch*4+kg)*96 + oc)*8 + j] = f2b(s);
    }
}

extern "C" void kernel_launch(void* const* d_in, const int* in_sizes, int n_in,
                              void* d_out, int out_size, void* d_ws, size_t ws_size,
                              hipStream_t stream)
{
    const float* x     = (const float*)d_in[0];
    const float* Lc_w1 = (const float*)d_in[1];
    const float* Lc_b1 = (const float*)d_in[2];
    const float* Lc_w2 = (const float*)d_in[3];
    const float* Lc_b2 = (const float*)d_in[4];
    const float* Rc_w1 = (const float*)d_in[5];
    const float* Rc_b1 = (const float*)d_in[6];
    const float* Rc_w2 = (const float*)d_in[7];
    const float* Rc_b2 = (const float*)d_in[8];
    const float* Lr_w  = (const float*)d_in[9];
    const float* Lr_b  = (const float*)d_in[10];
    const float* Rr_w  = (const float*)d_in[11];
    const float* Rr_b  = (const float*)d_in[12];
    const float* n1_w  = (const float*)d_in[13];
    const float* n1_b  = (const float*)d_in[14];
    const float* nL_w  = (const float*)d_in[15];
    const float* nL_b  = (const float*)d_in[16];
    const float* n2_w  = (const float*)d_in[17];
    const float* n2_b  = (const float*)d_in[18];
    const float* temp  = (const float*)d_in[19];
    const float* q_w   = (const float*)d_in[20];
    const float* qd_w  = (const float*)d_in[21];
    const float* kv_w  = (const float*)d_in[22];
    const float* kvd_w = (const float*)d_in[23];
    const float* po_w  = (const float*)d_in[24];
    const float* pi_w  = (const float*)d_in[25];
    const float* fdw_w = (const float*)d_in[26];
    const float* fpo_w = (const float*)d_in[27];

    char* base = (char*)d_ws;
    ushortT* xh   = (ushortT*)(base + 0);             // -> f0h (33.5M)
    ushortT* f0h  = (ushortT*)(base + 0);
    ushortT* Lh   = (ushortT*)(base + 33554432);      // -> kv0h (25.2M) -> f1h (33.5M)
    ushortT* kv0h = (ushortT*)(base + 33554432);
    ushortT* f1h  = (ushortT*)(base + 33554432);
    ushortT* Rh   = (ushortT*)(base + 67108864);      // -> vh -> x2nh
    ushortT* vh   = (ushortT*)(base + 67108864);
    ushortT* x2nh = (ushortT*)(base + 67108864);
    ushortT* illh = (ushortT*)(base + 79691776);
    ushortT* xnh  = (ushortT*)(base + 92274688);
    ushortT* q0h  = (ushortT*)(base + 104857600);
    ushortT* qb   = (ushortT*)(base + 117440512);     // bf16 NCHW q; x1 overlays after qk
    float*   x1   = (float*)(base + 117440512);
    ushortT* kb   = (ushortT*)(base + 142606336);     // bf16 NCHW k
    ushortT* Bb   = (ushortT*)(base + 155189248);     // R_rein bf16 NCHW
    char* smb = base + 167772160;
    ushortT* wpkL = (ushortT*)smb;   smb += 165888;
    ushortT* wpkR = (ushortT*)smb;   smb += 165888;
    ushortT* wpkQ = (ushortT*)smb;   smb += 165888;
    ushortT* wpkF = (ushortT*)smb;   smb += 1179648;
    ushortT* wq0  = (ushortT*)smb;   smb += 18432;
    ushortT* wkv  = (ushortT*)smb;   smb += 36864;
    ushortT* wpi  = (ushortT*)smb;   smb += 49152;
    ushortT* wfpo = (ushortT*)smb;   smb += 49152;
    ushortT* Mpk  = (ushortT*)smb;   smb += 73728;
    float* invqk  = (float*)smb;     smb += 3072;
    float* part   = (float*)smb;     smb += 2097152;
    float* araw   = (float*)smb;     smb += 65536;
    float* attn   = (float*)smb;     smb += 36864;

    float* out_x = (float*)d_out;
    float* out_L = out_x + (size_t)4*96*HWsz;
    float* out_R = out_L + (size_t)4*HWsz;

    dim3 blk(256);

    // ---- packing + input convert ----
    hipLaunchKernelGGL(pack_all_kernel, dim3(3576), blk, 0, stream,
        Lc_w1, Rc_w1, qd_w, fdw_w, q_w, kv_w, pi_w, fpo_w,
        wpkL, wpkR, wpkQ, wpkF, wq0, wkv, wpi, wfpo);
    hipLaunchKernelGGL(tonhwc_kernel, dim3(64,4), blk, 0, stream, x, xh);

    // ---- Retinex heads (Lc+Rc merged) ----
    hipLaunchKernelGGL((conv3x3_mfma<3,3,1,1,2>), dim3(64,4,4), blk, 0, stream,
        xh, wpkL, wpkR, Lc_b1, Rc_b1, (void*)Lh, (void*)Rh, 96, 96);
    hipLaunchKernelGGL((head1x1_kernel<1>), dim3(64,4), blk, 0, stream, Lh, Lc_w2, Lc_b2, out_L);
    hipLaunchKernelGGL((head1x1_kernel<3>), dim3(64,4), blk, 0, stream, Rh, Rc_w2, Rc_b2, out_R);
    hipLaunchKernelGGL(lrein_ln_kernel, dim3(64,4), blk, 0, stream, out_L, Lr_w, Lr_b, nL_w, nL_b, illh);
    hipLaunchKernelGGL((conv3x3_small_kernel<3,0>), dim3(64,96,4), blk, 0, stream, out_R, Rr_w, Rr_b, Bb);

    // ---- n1 norm ----
    hipLaunchKernelGGL(ln_n2n_kernel, dim3(64,4), blk, 0, stream, x, n1_w, n1_b, xnh);

    // ---- q path ----
    hipLaunchKernelGGL((gemm1x1_mfma<6,3,0,1>), dim3(64,1,4), blk, 0, stream,
        illh, wq0, 0, nullptr, nullptr, (void*)q0h, 96, 96);
    hipLaunchKernelGGL((conv3x3_mfma<2,3,0,2,0>), dim3(64,3,4), blk, 0, stream,
        q0h, wpkQ, wpkQ, nullptr, nullptr, (void*)qb, (void*)qb, 96, 0);
    // ---- kv path ----
    hipLaunchKernelGGL((gemm1x1_mfma<6,3,0,1>), dim3(64,2,4), blk, 0, stream,
        xnh, wkv, 0, nullptr, nullptr, (void*)kv0h, 192, 192);
    hipLaunchKernelGGL(dw_nhwc_kernel, dim3(64,24,4), blk, 0, stream, kv0h, kvd_w, kb, vh);

    // ---- attention ----
    hipLaunchKernelGGL(rownorm_bf16_kernel, dim3(768), blk, 0, stream, qb, kb, invqk);
    hipLaunchKernelGGL(qk_mfma_kernel, dim3(8,16), blk, 0, stream, qb, kb, part);
    hipLaunchKernelGGL(qk_reduce_kernel, dim3(64), blk, 0, stream, part, araw);
    hipLaunchKernelGGL(softmax_kernel, dim3(16), dim3(576), 0, stream, araw, invqk, invqk+384, temp, attn);
    hipLaunchKernelGGL(mkM_kernel, dim3(4), blk, 0, stream, attn, po_w, Mpk);
    // fused pv+po: x1 = x + M_b @ v
    hipLaunchKernelGGL((gemm1x1_mfma<6,3,1,0>), dim3(64,1,4), blk, 0, stream,
        vh, Mpk, 9216, x, nullptr, (void*)x1, 96, 0);

    // ---- FFN ----
    hipLaunchKernelGGL(ln_n2n_kernel, dim3(64,4), blk, 0, stream, x1, n2_w, n2_b, x2nh);
    hipLaunchKernelGGL((gemm1x1_mfma<4,3,0,1>), dim3(64,4,4), blk, 0, stream,
        x2nh, wpi, 0, nullptr, nullptr, (void*)f0h, 255, 256);
    hipLaunchKernelGGL((conv3x3_mfma<4,8,1,1,0>), dim3(64,4,4), blk, 0, stream,
        f0h, wpkF, wpkF, nullptr, nullptr, (void*)f1h, (void*)f1h, 255, 256);
    hipLaunchKernelGGL((gemm1x1_mfma<6,8,2,0>), dim3(64,1,4), blk, 0, stream,
        f1h, wfpo, 0, x1, Bb, (void*)out_x, 96, 0);
}

// Round 5
// 460.223 us; speedup vs baseline: 11.5155x; 1.1044x over previous
//
#include <hip/hip_runtime.h>

#define HWsz 16384
#define Wd 128

typedef unsigned short ushortT;
typedef unsigned int uintT;
typedef __attribute__((ext_vector_type(8))) short short8v;
typedef __attribute__((ext_vector_type(4))) float f32x4;
typedef __attribute__((ext_vector_type(16))) float f32x16;
typedef __attribute__((ext_vector_type(4))) unsigned short ushort4v;

__device__ __forceinline__ float gelu_f(float x){
    return 0.5f * x * (1.0f + erff(x * 0.70710678118654752f));
}
__device__ __forceinline__ ushortT f2b(float f){
    union { float f; uintT u; } v; v.f = f;
    uintT r = v.u + 0x7FFFu + ((v.u >> 16) & 1u);   // RNE
    return (ushortT)(r >> 16);
}
__device__ __forceinline__ float b2f(ushortT u){
    union { uintT u; float f; } v; v.u = ((uintT)u) << 16; return v.f;
}

// XCD-grouped decode: all nt/b instances of a tile land on one XCD.
// blocks = 8 * grp * (1<<ntlog) * 4 ; tiles = 8*grp
__device__ __forceinline__ void xdecode(int i, int ntlog, int& tile, int& nt, int& b){
    int xcd = i & 7, slot = i >> 3;
    int sub = slot & ((4 << ntlog) - 1);
    nt = sub & ((1 << ntlog) - 1);
    b  = sub >> ntlog;
    tile = xcd + 8 * (slot >> (ntlog + 2));
}

// ============ merged weight packing ============
__device__ __forceinline__ void pack3_one(int e, const float* __restrict__ w,
    ushortT* __restrict__ outp, int cout, int cin, int BN, int NCH)
{
    int j = e & 7; int r = e >> 3;
    int ocl = r % BN; r /= BN;
    int kg  = r & 3;  r >>= 2;
    int tap = r % 9;  r /= 9;
    int ch  = r % NCH;
    int nt  = r / NCH;
    int ci = ch*32 + kg*8 + j;
    int oc = nt*BN + ocl;
    float v = (oc < cout && ci < cin) ? w[((size_t)oc*cin + ci)*9 + tap] : 0.f;
    outp[e] = f2b(v);
}
__device__ __forceinline__ void pack1_one(int e, const float* __restrict__ w,
    ushortT* __restrict__ outp, int cout, int cin, int BN, int NCH)
{
    int j = e & 7; int r = e >> 3;
    int ocl = r % BN; r /= BN;
    int kg  = r & 3;  r >>= 2;
    int ch  = r % NCH;
    int nt  = r / NCH;
    int ci = ch*32 + kg*8 + j;
    int oc = nt*BN + ocl;
    float v = (oc < cout && ci < cin) ? w[(size_t)oc*cin + ci] : 0.f;
    outp[e] = f2b(v);
}
__global__ __launch_bounds__(256) void pack_all_kernel(
    const float* Lc, const float* Rc, const float* Qd, const float* Fd,
    const float* Q1, const float* KV1, const float* PI1, const float* FPO1,
    ushortT* dL, ushortT* dR, ushortT* dQ, ushortT* dF,
    ushortT* dq0, ushortT* dkv, ushortT* dpi, ushortT* dfpo)
{
    int e = blockIdx.x*256 + threadIdx.x;
    if      (e < 82944)  pack3_one(e,        Lc, dL, 96, 96, 48, 3);
    else if (e < 165888) pack3_one(e-82944,  Rc, dR, 96, 96, 48, 3);
    else if (e < 248832) pack3_one(e-165888, Qd, dQ, 96, 96, 32, 3);
    else if (e < 838656) pack3_one(e-248832, Fd, dF, 255,255, 64, 8);
    else if (e < 847872) pack1_one(e-838656, Q1, dq0, 96, 96, 96, 3);
    else if (e < 866304) pack1_one(e-847872, KV1,dkv, 192,96, 96, 3);
    else if (e < 890880) pack1_one(e-866304, PI1,dpi, 255,96, 64, 3);
    else if (e < 915456) pack1_one(e-890880, FPO1,dfpo,96,255, 96, 8);
}

// ============ x (NCHW fp32, 96ch) -> NHWC bf16 ============
__global__ __launch_bounds__(256) void tonhwc_kernel(
    const float* __restrict__ in, ushortT* __restrict__ outp)
{
    const int p = blockIdx.x*256 + threadIdx.x;
    const int b = blockIdx.y;
    const float* ip = in + (size_t)b*96*HWsz + p;
    ushortT* op = outp + ((size_t)b*HWsz + p)*96;
#pragma unroll
    for (int g=0; g<12; g++){
        float v[8];
#pragma unroll
        for (int c=0;c<8;c++) v[c] = ip[(size_t)(g*8+c)*HWsz];
        uint4 pk;
        pk.x = (uintT)f2b(v[0]) | ((uintT)f2b(v[1])<<16);
        pk.y = (uintT)f2b(v[2]) | ((uintT)f2b(v[3])<<16);
        pk.z = (uintT)f2b(v[4]) | ((uintT)f2b(v[5])<<16);
        pk.w = (uintT)f2b(v[6]) | ((uintT)f2b(v[7])<<16);
        *(uint4*)(op + g*8) = pk;
    }
}

// ============ MFMA implicit-GEMM 3x3 conv; B-frags from L2 ============
// OMODE: 0 fp32 NCHW, 1 bf16 NHWC[ocpad] (LDS-transpose epilogue), 2 bf16 NCHW.
// NSPLIT>0: nt >= NSPLIT selects second weight/bias/out set. XMAP>0: xcd decode with ntlog=XMAP-1.
template<int NG, int NCH, int ACT, int OMODE, int NSPLIT, int XMAP>
__global__ __launch_bounds__(256,4) void conv3x3_mfma(
    const ushortT* __restrict__ inh,
    const ushortT* __restrict__ wpk1, const ushortT* __restrict__ wpk2,
    const float* __restrict__ bias1, const float* __restrict__ bias2,
    void* __restrict__ out1, void* __restrict__ out2,
    int cout, int ocpad)
{
    constexpr int BN = NG*16;
    constexpr int Cpad = NCH*32;
    __shared__ __align__(16) ushortT As[4*324*8];

    const int tid = threadIdx.x;
    const int l   = tid & 63;
    const int wv  = tid >> 6;
    const int l15 = l & 15;
    const int kg  = l >> 4;

    int tile, nt, b;
    if (XMAP > 0){ xdecode(blockIdx.x, XMAP-1, tile, nt, b); }
    else { tile = blockIdx.x; nt = blockIdx.y; b = blockIdx.z; }
    const int tix = tile & 7, tiy = tile >> 3;

    const ushortT* wpk = wpk1; const float* bias = bias1; void* outv = out1;
    if (NSPLIT > 0 && nt >= NSPLIT){ nt -= NSPLIT; wpk = wpk2; bias = bias2; outv = out2; }

    f32x4 acc[4][NG];
#pragma unroll
    for (int m=0;m<4;m++)
#pragma unroll
        for (int n=0;n<NG;n++) acc[m][n] = (f32x4){0.f,0.f,0.f,0.f};

    const ushortT* inb = inh + (size_t)b*HWsz*Cpad;

    for (int ch=0; ch<NCH; ch++){
        __syncthreads();
#pragma unroll
        for (int g=0; g<4; g++){
            for (int p=tid; p<324; p+=256){
                int hy = p/18, hx = p - hy*18;
                int gy = tiy*16 + hy - 1, gx = tix*16 + hx - 1;
                uint4 v; v.x=0u; v.y=0u; v.z=0u; v.w=0u;
                if ((unsigned)gy < 128u && (unsigned)gx < 128u)
                    v = *(const uint4*)(inb + (size_t)(gy*Wd+gx)*Cpad + ch*32 + g*8);
                *(uint4*)(As + (g*324+p)*8) = v;
            }
        }
        __syncthreads();
        const ushortT* wch = wpk + (size_t)(nt*NCH + ch)*(9*4*BN*8);
#pragma unroll
        for (int tp=0; tp<9; tp++){
            const int dy = tp/3, dx = tp - dy*3;
            short8v a[4], bf[NG];
#pragma unroll
            for (int mg=0; mg<4; mg++){
                int p = (wv*4 + mg + dy)*18 + l15 + dx;
                a[mg] = *(const short8v*)(As + (kg*324 + p)*8);
            }
#pragma unroll
            for (int n=0;n<NG;n++)
                bf[n] = *(const short8v*)(wch + ((size_t)(tp*4 + kg)*BN + n*16 + l15)*8);
#pragma unroll
            for (int mg=0;mg<4;mg++)
#pragma unroll
                for (int n=0;n<NG;n++)
                    acc[mg][n] = __builtin_amdgcn_mfma_f32_16x16x32_bf16(a[mg], bf[n], acc[mg][n], 0,0,0);
        }
    }
    // D: col=lane&15 (oc), row=(lane>>4)*4+j (gx pixel)
    if (OMODE == 0){
        float* out = (float*)outv;
#pragma unroll
        for (int n=0;n<NG;n++){
            int oc = nt*BN + n*16 + l15;
            if (oc < cout){
                float bs = bias ? bias[oc] : 0.f;
#pragma unroll
                for (int mg=0;mg<4;mg++){
                    int gy = tiy*16 + wv*4 + mg;
                    int gx = tix*16 + kg*4;
                    float4 r;
                    r.x = acc[mg][n][0] + bs; r.y = acc[mg][n][1] + bs;
                    r.z = acc[mg][n][2] + bs; r.w = acc[mg][n][3] + bs;
                    if (ACT){ r.x=gelu_f(r.x); r.y=gelu_f(r.y); r.z=gelu_f(r.z); r.w=gelu_f(r.w); }
                    *(float4*)(out + ((size_t)b*cout + oc)*HWsz + gy*Wd + gx) = r;
                }
            }
        }
    } else if (OMODE == 1){
        // LDS-transpose epilogue -> coalesced 16B NHWC stores
        constexpr int LSTR = 64;   // BN <= 64 here
        constexpr int MASK = 7;
        __syncthreads();
        ushortT* Ts = As + wv*(16*LSTR);
        ushortT* outp = (ushortT*)outv;
#pragma unroll
        for (int mg=0;mg<4;mg++){
            int gy = tiy*16 + wv*4 + mg;
            ushortT* orow = outp + ((size_t)b*HWsz + gy*Wd + tix*16)*ocpad + nt*BN;
#pragma unroll
            for (int n=0;n<NG;n++){
                int ocl = n*16 + l15;
                int oc  = nt*BN + ocl;
                float bs = (bias && oc < cout) ? bias[oc] : 0.f;
#pragma unroll
                for (int j=0;j<4;j++){
                    int pxj = kg*4 + j;
                    float r = 0.f;
                    if (oc < cout){ r = acc[mg][n][j] + bs; if (ACT) r = gelu_f(r); }
                    int seg = ((ocl>>3) + pxj) & MASK;
                    Ts[pxj*LSTR + seg*8 + (ocl&7)] = f2b(r);
                }
            }
#pragma unroll
            for (int ps=0; ps < (BN+31)/32; ps++){
                int rpx = l & 15;
                int rs  = (l>>4) + ps*4;
                if (rs*8 < BN){
                    int pseg = (rs + rpx) & MASK;
                    short8v v = *(const short8v*)(Ts + rpx*LSTR + pseg*8);
                    *(short8v*)(orow + (size_t)rpx*ocpad + rs*8) = v;
                }
            }
        }
    } else {
        ushortT* out = (ushortT*)outv;
#pragma unroll
        for (int n=0;n<NG;n++){
            int oc = nt*BN + n*16 + l15;
            if (oc < cout){
                float bs = bias ? bias[oc] : 0.f;
#pragma unroll
                for (int mg=0;mg<4;mg++){
                    int gy = tiy*16 + wv*4 + mg;
                    int gx = tix*16 + kg*4;
                    ushort4v pk;
#pragma unroll
                    for (int j=0;j<4;j++){
                        float r = acc[mg][n][j] + bs;
                        if (ACT) r = gelu_f(r);
                        pk[j] = f2b(r);
                    }
                    *(ushort4v*)(out + ((size_t)b*cout + oc)*HWsz + gy*Wd + gx) = pk;
                }
            }
        }
    }
}

// ============ MFMA 1x1 GEMM ============
// RES: 0 none; 1 +res1(fp32); 2 +res1(fp32)+res2b(bf16 NCHW). OMODE: 0 fp32 NCHW, 1 bf16 NHWC.
template<int NG, int NCH, int RES, int OMODE, int XMAP>
__global__ __launch_bounds__(256) void gemm1x1_mfma(
    const ushortT* __restrict__ inh, const ushortT* __restrict__ wpk, int wstride_z,
    const float* __restrict__ res1, const ushortT* __restrict__ res2b,
    void* __restrict__ outv, int cout, int ocpad)
{
    constexpr int BN = NG*16;
    constexpr int Cpad = NCH*32;
    constexpr int LSTR = (BN <= 64) ? 64 : 128;
    constexpr int MASK = LSTR/8 - 1;
    __shared__ __align__(16) ushortT TsS[(OMODE==1) ? 4*16*LSTR : 16];

    const int tid = threadIdx.x;
    const int l = tid & 63, wv = tid >> 6, l15 = l & 15, kg = l >> 4;

    int chunk, nt, b;
    if (XMAP > 0){ xdecode(blockIdx.x, XMAP-1, chunk, nt, b); }
    else { chunk = blockIdx.x; nt = blockIdx.y; b = blockIdx.z; }
    const int p0 = chunk*256 + wv*64;
    const ushortT* inb = inh + (size_t)b*HWsz*Cpad;
    const ushortT* wp  = wpk + (size_t)b*wstride_z;

    f32x4 acc[4][NG];
#pragma unroll
    for (int m=0;m<4;m++)
#pragma unroll
        for (int n=0;n<NG;n++) acc[m][n] = (f32x4){0.f,0.f,0.f,0.f};

#pragma unroll
    for (int ch=0; ch<NCH; ch++){
        short8v a[4], bw[NG];
#pragma unroll
        for (int mg=0; mg<4; mg++)
            a[mg] = *(const short8v*)(inb + (size_t)(p0 + mg*16 + l15)*Cpad + ch*32 + kg*8);
#pragma unroll
        for (int n=0;n<NG;n++)
            bw[n] = *(const short8v*)(wp + (((size_t)(nt*NCH + ch)*4 + kg)*BN + n*16 + l15)*8);
#pragma unroll
        for (int mg=0;mg<4;mg++)
#pragma unroll
            for (int n=0;n<NG;n++)
                acc[mg][n] = __builtin_amdgcn_mfma_f32_16x16x32_bf16(a[mg], bw[n], acc[mg][n], 0,0,0);
    }
    if (OMODE == 0){
        float* out = (float*)outv;
#pragma unroll
        for (int n=0;n<NG;n++){
            int oc = nt*BN + n*16 + l15;
            if (oc < cout){
#pragma unroll
                for (int mg=0;mg<4;mg++){
                    int pix = p0 + mg*16 + kg*4;
                    size_t idx = ((size_t)b*cout + oc)*HWsz + pix;
                    float4 r;
                    r.x = acc[mg][n][0]; r.y = acc[mg][n][1];
                    r.z = acc[mg][n][2]; r.w = acc[mg][n][3];
                    if (RES>=1){ float4 q = *(const float4*)(res1+idx); r.x+=q.x;r.y+=q.y;r.z+=q.z;r.w+=q.w; }
                    if (RES>=2){
                        ushort4v q = *(const ushort4v*)(res2b+idx);
                        r.x+=b2f(q[0]); r.y+=b2f(q[1]); r.z+=b2f(q[2]); r.w+=b2f(q[3]);
                    }
                    *(float4*)(out + idx) = r;
                }
            }
        }
    } else {
        ushortT* outp = (ushortT*)outv;
        ushortT* Ts = TsS + wv*(16*LSTR);
#pragma unroll
        for (int mg=0;mg<4;mg++){
            ushortT* orow = outp + ((size_t)b*HWsz + p0 + mg*16)*ocpad + nt*BN;
#pragma unroll
            for (int n=0;n<NG;n++){
                int ocl = n*16 + l15;
                int oc  = nt*BN + ocl;
#pragma unroll
                for (int j=0;j<4;j++){
                    int pxj = kg*4 + j;
                    float r = (oc < cout) ? acc[mg][n][j] : 0.f;
                    int seg = ((ocl>>3) + pxj) & MASK;
                    Ts[pxj*LSTR + seg*8 + (ocl&7)] = f2b(r);
                }
            }
#pragma unroll
            for (int ps=0; ps < (BN+31)/32; ps++){
                int rpx = l & 15;
                int rs  = (l>>4) + ps*4;
                if (rs*8 < BN){
                    int pseg = (rs + rpx) & MASK;
                    short8v v = *(const short8v*)(Ts + rpx*LSTR + pseg*8);
                    *(short8v*)(orow + (size_t)rpx*ocpad + rs*8) = v;
                }
            }
        }
    }
}

// ============ head 1x1 (96 -> NOUT), NHWC bf16 in, NCHW fp32 out ============
template<int NOUT>
__global__ __launch_bounds__(256) void head1x1_kernel(
    const ushortT* __restrict__ inh, const float* __restrict__ w,
    const float* __restrict__ bias, float* __restrict__ out)
{
    __shared__ float lw[NOUT*96];
    const int tid = threadIdx.x;
    for (int t=tid; t<NOUT*96; t+=256) lw[t] = w[t];
    __syncthreads();
    const int p = blockIdx.x*256 + tid;
    const int b = blockIdx.y;
    const ushortT* ip = inh + ((size_t)b*HWsz + p)*96;
    float v[96];
#pragma unroll
    for (int g=0; g<12; g++){
        short8v s = *(const short8v*)(ip + g*8);
#pragma unroll
        for (int i=0;i<8;i++) v[g*8+i] = b2f((ushortT)s[i]);
    }
#pragma unroll
    for (int oc=0; oc<NOUT; oc++){
        float acc = bias[oc];
#pragma unroll
        for (int c=0;c<96;c++) acc += v[c]*lw[oc*96+c];
        out[((size_t)b*NOUT + oc)*HWsz + p] = acc;
    }
}

// ============ fused: Lr conv3x3(1->96)+bias+GELU + LayerNorm(nL) -> illh bf16 NHWC ============
__global__ __launch_bounds__(256) void lrein_ln_kernel(
    const float* __restrict__ L, const float* __restrict__ w,
    const float* __restrict__ bias, const float* __restrict__ lnw,
    const float* __restrict__ lnb, ushortT* __restrict__ outh)
{
    __shared__ float sw[864], sb[96], sn1[96], sn2[96];
    const int tid = threadIdx.x;
    for (int t=tid; t<864; t+=256) sw[t] = w[t];
    if (tid < 96){ sb[tid]=bias[tid]; sn1[tid]=lnw[tid]; sn2[tid]=lnb[tid]; }
    __syncthreads();
    const int p = blockIdx.x*256 + tid;
    const int b = blockIdx.y;
    const int y = p>>7, x = p&127;
    const float* ib = L + (size_t)b*HWsz;
    float win[9];
#pragma unroll
    for (int dy=0;dy<3;dy++)
#pragma unroll
        for (int dx=0;dx<3;dx++){
            int gy=y+dy-1, gx=x+dx-1;
            win[dy*3+dx] = ((unsigned)gy<128u && (unsigned)gx<128u) ? ib[gy*Wd+gx] : 0.f;
        }
    float v[96]; float s=0.f;
#pragma unroll
    for (int c=0;c<96;c++){
        float a = sb[c];
#pragma unroll
        for (int t=0;t<9;t++) a += win[t]*sw[c*9+t];
        a = gelu_f(a);
        v[c]=a; s+=a;
    }
    const float mu = s*(1.f/96.f);
    float s2=0.f;
#pragma unroll
    for (int c=0;c<96;c++){ float d=v[c]-mu; s2+=d*d; }
    const float inv = 1.f/sqrtf(s2*(1.f/96.f)+1e-5f);
    ushortT* op = outh + ((size_t)b*HWsz + p)*96;
#pragma unroll
    for (int g=0; g<12; g++){
        uint4 pk; uintT w4[4];
#pragma unroll
        for (int i=0;i<4;i++){
            float r0 = (v[g*8+2*i]-mu)*inv*sn1[g*8+2*i]+sn2[g*8+2*i];
            float r1 = (v[g*8+2*i+1]-mu)*inv*sn1[g*8+2*i+1]+sn2[g*8+2*i+1];
            w4[i] = (uintT)f2b(r0) | ((uintT)f2b(r1)<<16);
        }
        pk.x=w4[0]; pk.y=w4[1]; pk.z=w4[2]; pk.w=w4[3];
        *(uint4*)(op + g*8) = pk;
    }
}

// ============ LayerNorm: NCHW fp32 -> NHWC bf16 ============
__global__ __launch_bounds__(256) void ln_n2n_kernel(
    const float* __restrict__ in, const float* __restrict__ w,
    const float* __restrict__ bias, ushortT* __restrict__ outh)
{
    const int p = blockIdx.x*256+threadIdx.x;
    const int b = blockIdx.y;
    const float* ip = in + (size_t)b*96*HWsz + p;
    float v[96]; float s=0.f;
#pragma unroll
    for(int c=0;c<96;c++){ v[c]=ip[(size_t)c*HWsz]; s+=v[c]; }
    const float mu = s*(1.f/96.f);
    float s2=0.f;
#pragma unroll
    for(int c=0;c<96;c++){ float d=v[c]-mu; s2+=d*d; }
    const float inv = 1.f/sqrtf(s2*(1.f/96.f)+1e-5f);
    ushortT* op = outh + ((size_t)b*HWsz + p)*96;
#pragma unroll
    for (int g=0; g<12; g++){
        uint4 pk; uintT w4[4];
#pragma unroll
        for (int i=0;i<4;i++){
            float r0 = (v[g*8+2*i]-mu)*inv*w[g*8+2*i]+bias[g*8+2*i];
            float r1 = (v[g*8+2*i+1]-mu)*inv*w[g*8+2*i+1]+bias[g*8+2*i+1];
            w4[i] = (uintT)f2b(r0) | ((uintT)f2b(r1)<<16);
        }
        pk.x=w4[0]; pk.y=w4[1]; pk.z=w4[2]; pk.w=w4[3];
        *(uint4*)(op + g*8) = pk;
    }
}

// ============ Rr 3->96, 8 oc per block -> bf16 NCHW ============
__global__ __launch_bounds__(256) void conv3x3_rr_kernel(
    const float* __restrict__ in, const float* __restrict__ w,
    const float* __restrict__ bias, ushortT* __restrict__ out)
{
    __shared__ float sw[216], sb[8];
    const int oc0 = blockIdx.y*8;
    if (threadIdx.x < 216) sw[threadIdx.x] = w[(size_t)oc0*27 + threadIdx.x];
    if (threadIdx.x < 8)   sb[threadIdx.x] = bias[oc0 + threadIdx.x];
    __syncthreads();
    const int p = blockIdx.x*256+threadIdx.x;
    const int b = blockIdx.z;
    const int y=p>>7, x=p&127;
    const float* ib = in + (size_t)b*3*HWsz;
    float win[27];
#pragma unroll
    for (int ci=0;ci<3;ci++)
#pragma unroll
        for (int dy=0;dy<3;dy++)
#pragma unroll
            for (int dx=0;dx<3;dx++){
                int gy=y+dy-1, gx=x+dx-1;
                win[ci*9+dy*3+dx] = ((unsigned)gy<128u && (unsigned)gx<128u)
                    ? ib[(size_t)ci*HWsz + gy*Wd+gx] : 0.f;
            }
#pragma unroll
    for (int i=0;i<8;i++){
        float acc = sb[i];
#pragma unroll
        for (int t=0;t<27;t++) acc += win[t]*sw[i*27+t];
        out[((size_t)b*96 + oc0+i)*HWsz + p] = f2b(acc);
    }
}

// ============ depthwise 3x3 NHWC bf16; k-half -> bf16 NCHW, v-half -> bf16 NHWC ============
__global__ __launch_bounds__(256) void dw_nhwc_kernel(
    const ushortT* __restrict__ inh, const float* __restrict__ w,
    ushortT* __restrict__ kout, ushortT* __restrict__ vouth)
{
    const int p = blockIdx.x*256+threadIdx.x;
    const int c0 = blockIdx.y*8;
    const int b = blockIdx.z;
    const int y=p>>7, x=p&127;
    float lw[72];
#pragma unroll
    for (int i=0;i<8;i++)
#pragma unroll
        for (int t=0;t<9;t++) lw[i*9+t] = w[(size_t)(c0+i)*9 + t];
    const ushortT* ib = inh + (size_t)b*HWsz*192;
    float acc[8];
#pragma unroll
    for (int i=0;i<8;i++) acc[i]=0.f;
#pragma unroll
    for(int dy=0;dy<3;dy++){
        int gy=y+dy-1;
        if((unsigned)gy<128u){
#pragma unroll
            for(int dx=0;dx<3;dx++){
                int gx=x+dx-1;
                if((unsigned)gx<128u){
                    short8v s = *(const short8v*)(ib + (size_t)(gy*Wd+gx)*192 + c0);
#pragma unroll
                    for (int i=0;i<8;i++) acc[i] += b2f((ushortT)s[i])*lw[i*9+dy*3+dx];
                }
            }
        }
    }
    if (c0 < 96){
#pragma unroll
        for (int i=0;i<8;i++)
            kout[((size_t)b*96 + c0+i)*HWsz + p] = f2b(acc[i]);
    } else {
        ushortT* op = vouth + ((size_t)b*HWsz + p)*96 + (c0-96);
        uint4 pk;
        pk.x = (uintT)f2b(acc[0]) | ((uintT)f2b(acc[1])<<16);
        pk.y = (uintT)f2b(acc[2]) | ((uintT)f2b(acc[3])<<16);
        pk.z = (uintT)f2b(acc[4]) | ((uintT)f2b(acc[5])<<16);
        pk.w = (uintT)f2b(acc[6]) | ((uintT)f2b(acc[7])<<16);
        *(uint4*)op = pk;
    }
}

// ============ row L2-norm reciprocals for q/k (bf16 NCHW) ============
__global__ __launch_bounds__(256) void rownorm_bf16_kernel(
    const ushortT* __restrict__ qb, const ushortT* __restrict__ kb,
    float* __restrict__ invqk)
{
    __shared__ float red[256];
    const int r = blockIdx.x;       // 0..767
    const ushortT* ip = (r < 384) ? (qb + (size_t)r*HWsz) : (kb + (size_t)(r-384)*HWsz);
    float s=0.f;
    const ushortT* tp = ip + threadIdx.x*64;
#pragma unroll
    for (int g=0; g<8; g++){
        short8v v = *(const short8v*)(tp + g*8);
#pragma unroll
        for (int i=0;i<8;i++){ float f = b2f((ushortT)v[i]); s += f*f; }
    }
    red[threadIdx.x]=s; __syncthreads();
    for(int st=128; st>0; st>>=1){
        if(threadIdx.x<st) red[threadIdx.x]+=red[threadIdx.x+st];
        __syncthreads();
    }
    if(threadIdx.x==0) invqk[r] = 1.f/fmaxf(sqrtf(red[0]), 1e-12f);
}

// ============ QK^T Gram via MFMA 32x32x16 ============
__global__ __launch_bounds__(256) void qk_mfma_kernel(
    const ushortT* __restrict__ qb, const ushortT* __restrict__ kb,
    float* __restrict__ part)
{
    const int tid = threadIdx.x;
    const int l = tid & 63, wv = tid >> 6;
    const int chunk = blockIdx.x*4 + wv;          // 0..31
    const int bh = blockIdx.y, b = bh>>2, h = bh&3;
    const int ch = min(l & 31, 23);
    const int kh = (l >> 5)*8;
    const ushortT* qp = qb + ((size_t)b*96 + h*24 + ch)*HWsz + chunk*512 + kh;
    const ushortT* kp = kb + ((size_t)b*96 + h*24 + ch)*HWsz + chunk*512 + kh;
    f32x16 acc;
#pragma unroll
    for (int r=0;r<16;r++) acc[r]=0.f;
    for (int ks=0; ks<32; ks++){
        short8v a  = *(const short8v*)(qp + ks*16);
        short8v bb = *(const short8v*)(kp + ks*16);
        acc = __builtin_amdgcn_mfma_f32_32x32x16_bf16(a, bb, acc, 0,0,0);
    }
    float* op = part + ((size_t)chunk*16 + bh)*1024;
    const int col = l & 31;
#pragma unroll
    for (int r=0;r<16;r++){
        int row = (r&3) + 8*(r>>2) + 4*(l>>5);
        op[row*32 + col] = acc[r];
    }
}

__global__ void qk_reduce_kernel(const float* __restrict__ part, float* __restrict__ out)
{
    int idx = blockIdx.x*256+threadIdx.x;      // 16*1024
    float s=0.f;
    for(int c=0;c<32;c++) s += part[(size_t)c*16384 + idx];
    out[idx]=s;
}

// ============ softmax over 24 cols (norms + temp folded) ============
__global__ __launch_bounds__(576) void softmax_kernel(
    const float* __restrict__ raw, const float* __restrict__ invq,
    const float* __restrict__ invk, const float* __restrict__ temp,
    float* __restrict__ attn)
{
    __shared__ float l[576];
    const int bh=blockIdx.x, b=bh>>2, h=bh&3;
    const int tid=threadIdx.x;
    const int i=tid/24, j=tid-i*24;
    l[tid] = raw[(size_t)bh*1024 + i*32 + j] * invq[b*96+h*24+i] * invk[b*96+h*24+j] * temp[h];
    __syncthreads();
    if(tid<24){
        float m=-1e30f;
#pragma unroll
        for(int jj=0;jj<24;jj++) m = fmaxf(m, l[tid*24+jj]);
        float e[24]; float s=0.f;
#pragma unroll
        for(int jj=0;jj<24;jj++){ e[jj]=__expf(l[tid*24+jj]-m); s+=e[jj]; }
        float isv = 1.f/s;
#pragma unroll
        for(int jj=0;jj<24;jj++) attn[(size_t)bh*576 + tid*24 + jj] = e[jj]*isv;
    }
}

// ============ M_b = po_w @ blockdiag(attn_b), packed to B-frag bf16 ============
__global__ __launch_bounds__(256) void mkM_kernel(
    const float* __restrict__ attn, const float* __restrict__ po_w,
    ushortT* __restrict__ Mpk)
{
    const int b = blockIdx.x;
    for (int e = threadIdx.x; e < 9216; e += 256){
        int oc = e / 96, d = e - oc*96;
        int h = d / 24, dl = d - h*24;
        const float* aw = attn + ((size_t)(b*4+h))*576 + dl;
        const float* pw = po_w + (size_t)oc*96 + h*24;
        float s = 0.f;
#pragma unroll
        for (int c=0;c<24;c++) s += pw[c]*aw[c*24];
        int ch = d>>5, kg = (d>>3)&3, j = d&7;
        Mpk[(size_t)b*9216 + ((size_t)(ch*4+kg)*96 + oc)*8 + j] = f2b(s);
    }
}

extern "C" void kernel_launch(void* const* d_in, const int* in_sizes, int n_in,
                              void* d_out, int out_size, void* d_ws, size_t ws_size,
                              hipStream_t stream)
{
    const float* x     = (const float*)d_in[0];
    const float* Lc_w1 = (const float*)d_in[1];
    const float* Lc_b1 = (const float*)d_in[2];
    const float* Lc_w2 = (const float*)d_in[3];
    const float* Lc_b2 = (const float*)d_in[4];
    const float* Rc_w1 = (const float*)d_in[5];
    const float* Rc_b1 = (const float*)d_in[6];
    const float* Rc_w2 = (const float*)d_in[7];
    const float* Rc_b2 = (const float*)d_in[8];
    const float* Lr_w  = (const float*)d_in[9];
    const float* Lr_b  = (const float*)d_in[10];
    const float* Rr_w  = (const float*)d_in[11];
    const float* Rr_b  = (const float*)d_in[12];
    const float* n1_w  = (const float*)d_in[13];
    const float* n1_b  = (const float*)d_in[14];
    const float* nL_w  = (const float*)d_in[15];
    const float* nL_b  = (const float*)d_in[16];
    const float* n2_w  = (const float*)d_in[17];
    const float* n2_b  = (const float*)d_in[18];
    const float* temp  = (const float*)d_in[19];
    const float* q_w   = (const float*)d_in[20];
    const float* qd_w  = (const float*)d_in[21];
    const float* kv_w  = (const float*)d_in[22];
    const float* kvd_w = (const float*)d_in[23];
    const float* po_w  = (const float*)d_in[24];
    const float* pi_w  = (const float*)d_in[25];
    const float* fdw_w = (const float*)d_in[26];
    const float* fpo_w = (const float*)d_in[27];

    char* base = (char*)d_ws;
    ushortT* xh   = (ushortT*)(base + 0);
    ushortT* f0h  = (ushortT*)(base + 0);
    ushortT* Lh   = (ushortT*)(base + 33554432);
    ushortT* kv0h = (ushortT*)(base + 33554432);
    ushortT* f1h  = (ushortT*)(base + 33554432);
    ushortT* Rh   = (ushortT*)(base + 67108864);
    ushortT* vh   = (ushortT*)(base + 67108864);
    ushortT* x2nh = (ushortT*)(base + 67108864);
    ushortT* illh = (ushortT*)(base + 79691776);
    ushortT* xnh  = (ushortT*)(base + 92274688);
    ushortT* q0h  = (ushortT*)(base + 104857600);
    ushortT* qb   = (ushortT*)(base + 117440512);
    float*   x1   = (float*)(base + 117440512);
    ushortT* kb   = (ushortT*)(base + 142606336);
    ushortT* Bb   = (ushortT*)(base + 155189248);
    char* smb = base + 167772160;
    ushortT* wpkL = (ushortT*)smb;   smb += 165888;
    ushortT* wpkR = (ushortT*)smb;   smb += 165888;
    ushortT* wpkQ = (ushortT*)smb;   smb += 165888;
    ushortT* wpkF = (ushortT*)smb;   smb += 1179648;
    ushortT* wq0  = (ushortT*)smb;   smb += 18432;
    ushortT* wkv  = (ushortT*)smb;   smb += 36864;
    ushortT* wpi  = (ushortT*)smb;   smb += 49152;
    ushortT* wfpo = (ushortT*)smb;   smb += 49152;
    ushortT* Mpk  = (ushortT*)smb;   smb += 73728;
    float* invqk  = (float*)smb;     smb += 3072;
    float* part   = (float*)smb;     smb += 2097152;
    float* araw   = (float*)smb;     smb += 65536;
    float* attn   = (float*)smb;     smb += 36864;

    float* out_x = (float*)d_out;
    float* out_L = out_x + (size_t)4*96*HWsz;
    float* out_R = out_L + (size_t)4*HWsz;

    dim3 blk(256);

    // ---- packing + input convert ----
    hipLaunchKernelGGL(pack_all_kernel, dim3(3576), blk, 0, stream,
        Lc_w1, Rc_w1, qd_w, fdw_w, q_w, kv_w, pi_w, fpo_w,
        wpkL, wpkR, wpkQ, wpkF, wq0, wkv, wpi, wfpo);
    hipLaunchKernelGGL(tonhwc_kernel, dim3(64,4), blk, 0, stream, x, xh);

    // ---- Retinex heads (Lc+Rc merged, XCD-grouped) ----
    hipLaunchKernelGGL((conv3x3_mfma<3,3,1,1,2,3>), dim3(1024), blk, 0, stream,
        xh, wpkL, wpkR, Lc_b1, Rc_b1, (void*)Lh, (void*)Rh, 96, 96);
    hipLaunchKernelGGL((head1x1_kernel<1>), dim3(64,4), blk, 0, stream, Lh, Lc_w2, Lc_b2, out_L);
    hipLaunchKernelGGL((head1x1_kernel<3>), dim3(64,4), blk, 0, stream, Rh, Rc_w2, Rc_b2, out_R);
    hipLaunchKernelGGL(lrein_ln_kernel, dim3(64,4), blk, 0, stream, out_L, Lr_w, Lr_b, nL_w, nL_b, illh);
    hipLaunchKernelGGL(conv3x3_rr_kernel, dim3(64,12,4), blk, 0, stream, out_R, Rr_w, Rr_b, Bb);

    // ---- n1 norm ----
    hipLaunchKernelGGL(ln_n2n_kernel, dim3(64,4), blk, 0, stream, x, n1_w, n1_b, xnh);

    // ---- q path ----
    hipLaunchKernelGGL((gemm1x1_mfma<6,3,0,1,0>), dim3(64,1,4), blk, 0, stream,
        illh, wq0, 0, nullptr, nullptr, (void*)q0h, 96, 96);
    hipLaunchKernelGGL((conv3x3_mfma<2,3,0,2,0,0>), dim3(64,3,4), blk, 0, stream,
        q0h, wpkQ, wpkQ, nullptr, nullptr, (void*)qb, (void*)qb, 96, 0);
    // ---- kv path ----
    hipLaunchKernelGGL((gemm1x1_mfma<6,3,0,1,2>), dim3(512), blk, 0, stream,
        xnh, wkv, 0, nullptr, nullptr, (void*)kv0h, 192, 192);
    hipLaunchKernelGGL(dw_nhwc_kernel, dim3(64,24,4), blk, 0, stream, kv0h, kvd_w, kb, vh);

    // ---- attention ----
    hipLaunchKernelGGL(rownorm_bf16_kernel, dim3(768), blk, 0, stream, qb, kb, invqk);
    hipLaunchKernelGGL(qk_mfma_kernel, dim3(8,16), blk, 0, stream, qb, kb, part);
    hipLaunchKernelGGL(qk_reduce_kernel, dim3(64), blk, 0, stream, part, araw);
    hipLaunchKernelGGL(softmax_kernel, dim3(16), dim3(576), 0, stream, araw, invqk, invqk+384, temp, attn);
    hipLaunchKernelGGL(mkM_kernel, dim3(4), blk, 0, stream, attn, po_w, Mpk);
    // fused pv+po: x1 = x + M_b @ v
    hipLaunchKernelGGL((gemm1x1_mfma<6,3,1,0,0>), dim3(64,1,4), blk, 0, stream,
        vh, Mpk, 9216, x, nullptr, (void*)x1, 96, 0);

    // ---- FFN ----
    hipLaunchKernelGGL(ln_n2n_kernel, dim3(64,4), blk, 0, stream, x1, n2_w, n2_b, x2nh);
    hipLaunchKernelGGL((gemm1x1_mfma<4,3,0,1,3>), dim3(1024), blk, 0, stream,
        x2nh, wpi, 0, nullptr, nullptr, (void*)f0h, 255, 256);
    hipLaunchKernelGGL((conv3x3_mfma<4,8,1,1,0,3>), dim3(1024), blk, 0, stream,
        f0h, wpkF, wpkF, nullptr, nullptr, (void*)f1h, (void*)f1h, 255, 256);
    hipLaunchKernelGGL((gemm1x1_mfma<6,8,2,0,0>), dim3(64,1,4), blk, 0, stream,
        f1h, wfpo, 0, x1, Bb, (void*)out_x, 96, 0);
}

// Round 6
// 408.098 us; speedup vs baseline: 12.9863x; 1.1277x over previous
//
#include <hip/hip_runtime.h>

#define HWsz 16384
#define Wd 128

typedef unsigned short ushortT;
typedef unsigned int uintT;
typedef __attribute__((ext_vector_type(8))) short short8v;
typedef __attribute__((ext_vector_type(4))) float f32x4;
typedef __attribute__((ext_vector_type(16))) float f32x16;
typedef __attribute__((ext_vector_type(4))) unsigned short ushort4v;

__device__ __forceinline__ float gelu_f(float x){
    return 0.5f * x * (1.0f + erff(x * 0.70710678118654752f));
}
__device__ __forceinline__ ushortT f2b(float f){
    union { float f; uintT u; } v; v.f = f;
    uintT r = v.u + 0x7FFFu + ((v.u >> 16) & 1u);   // RNE
    return (ushortT)(r >> 16);
}
__device__ __forceinline__ float b2f(ushortT u){
    union { uintT u; float f; } v; v.u = ((uintT)u) << 16; return v.f;
}

// ============ merged weight packing ============
__device__ __forceinline__ void pack3_one(int e, const float* __restrict__ w,
    ushortT* __restrict__ outp, int cout, int cin, int BN, int NCH)
{
    int j = e & 7; int r = e >> 3;
    int ocl = r % BN; r /= BN;
    int kg  = r & 3;  r >>= 2;
    int tap = r % 9;  r /= 9;
    int ch  = r % NCH;
    int nt  = r / NCH;
    int ci = ch*32 + kg*8 + j;
    int oc = nt*BN + ocl;
    float v = (oc < cout && ci < cin) ? w[((size_t)oc*cin + ci)*9 + tap] : 0.f;
    outp[e] = f2b(v);
}
__device__ __forceinline__ void pack1_one(int e, const float* __restrict__ w,
    ushortT* __restrict__ outp, int cout, int cin, int BN, int NCH)
{
    int j = e & 7; int r = e >> 3;
    int ocl = r % BN; r /= BN;
    int kg  = r & 3;  r >>= 2;
    int ch  = r % NCH;
    int nt  = r / NCH;
    int ci = ch*32 + kg*8 + j;
    int oc = nt*BN + ocl;
    float v = (oc < cout && ci < cin) ? w[(size_t)oc*cin + ci] : 0.f;
    outp[e] = f2b(v);
}
__global__ __launch_bounds__(256) void pack_all_kernel(
    const float* Lc, const float* Rc, const float* Qd, const float* Fd,
    const float* Q1, const float* KV1, const float* PI1, const float* FPO1,
    ushortT* dL, ushortT* dR, ushortT* dQ, ushortT* dF,
    ushortT* dq0, ushortT* dkv, ushortT* dpi, ushortT* dfpo)
{
    int e = blockIdx.x*256 + threadIdx.x;
    if      (e < 82944)  pack3_one(e,        Lc, dL, 96, 96, 48, 3);
    else if (e < 165888) pack3_one(e-82944,  Rc, dR, 96, 96, 48, 3);
    else if (e < 248832) pack3_one(e-165888, Qd, dQ, 96, 96, 32, 3);
    else if (e < 838656) pack3_one(e-248832, Fd, dF, 255,255, 64, 8);
    else if (e < 847872) pack1_one(e-838656, Q1, dq0, 96, 96, 96, 3);
    else if (e < 866304) pack1_one(e-847872, KV1,dkv, 192,96, 48, 3);
    else if (e < 890880) pack1_one(e-866304, PI1,dpi, 255,96, 64, 3);
    else if (e < 915456) pack1_one(e-890880, FPO1,dfpo,96,255, 96, 8);
}

// ============ x (NCHW fp32, 96ch) -> NHWC bf16 ============
__global__ __launch_bounds__(256) void tonhwc_kernel(
    const float* __restrict__ in, ushortT* __restrict__ outp)
{
    const int p = blockIdx.x*256 + threadIdx.x;
    const int b = blockIdx.y;
    const float* ip = in + (size_t)b*96*HWsz + p;
    ushortT* op = outp + ((size_t)b*HWsz + p)*96;
#pragma unroll
    for (int g=0; g<12; g++){
        float v[8];
#pragma unroll
        for (int c=0;c<8;c++) v[c] = ip[(size_t)(g*8+c)*HWsz];
        uint4 pk;
        pk.x = (uintT)f2b(v[0]) | ((uintT)f2b(v[1])<<16);
        pk.y = (uintT)f2b(v[2]) | ((uintT)f2b(v[3])<<16);
        pk.z = (uintT)f2b(v[4]) | ((uintT)f2b(v[5])<<16);
        pk.w = (uintT)f2b(v[6]) | ((uintT)f2b(v[7])<<16);
        *(uint4*)(op + g*8) = pk;
    }
}

// ============ conv3x3 v2: one block = 16x8 pixel tile x ALL output channels ============
// 4 waves = 4 oc-groups. TWOOUT=0: wave wv -> ocs [wv*BN,(wv+1)*BN) of out1.
// TWOOUT=1: waves 0,1 -> out1 ocs [0,2*BN); waves 2,3 -> out2 ocs [0,2*BN).
// in NHWC bf16 [b][p][Cpad]; out NHWC bf16 [b][p][ocpad]. grid (128,1,B).
template<int NG, int NCH, int ACT, int TWOOUT>
__global__ __launch_bounds__(256,2) void conv3x3_v2(
    const ushortT* __restrict__ inh,
    const ushortT* __restrict__ wpk1, const ushortT* __restrict__ wpk2,
    const float* __restrict__ bias1, const float* __restrict__ bias2,
    ushortT* __restrict__ out1, ushortT* __restrict__ out2,
    int cout, int ocpad)
{
    constexpr int BN = NG*16;
    constexpr int Cpad = NCH*32;
    __shared__ __align__(16) ushortT As[4*180*8];   // [g][p(18x10)][8ci]

    const int tid = threadIdx.x;
    const int l   = tid & 63;
    const int wv  = tid >> 6;
    const int l15 = l & 15;
    const int kg  = l >> 4;
    const int tix = blockIdx.x & 7, tiy = blockIdx.x >> 3;   // 8 x-tiles, 16 y-tiles
    const int b   = blockIdx.z;
    const int x0 = tix*16, y0 = tiy*8;

    const ushortT* wpk; const float* bias; ushortT* outp; int nt;
    if (TWOOUT){
        wpk  = (wv >= 2) ? wpk2 : wpk1;
        bias = (wv >= 2) ? bias2 : bias1;
        outp = (wv >= 2) ? out2 : out1;
        nt = wv & 1;
    } else { wpk = wpk1; bias = bias1; outp = out1; nt = wv; }
    const int ocbase = nt*BN;

    f32x4 acc[8][NG];
#pragma unroll
    for (int m=0;m<8;m++)
#pragma unroll
        for (int n=0;n<NG;n++) acc[m][n] = (f32x4){0.f,0.f,0.f,0.f};

    const ushortT* inb = inh + (size_t)b*HWsz*Cpad;

    for (int ch=0; ch<NCH; ch++){
        __syncthreads();
#pragma unroll
        for (int g=0; g<4; g++){
            int p = tid;
            if (p < 180){
                int hy = p/18, hx = p - hy*18;
                int gy = y0 + hy - 1, gx = x0 + hx - 1;
                uint4 v; v.x=0u; v.y=0u; v.z=0u; v.w=0u;
                if ((unsigned)gy < 128u && (unsigned)gx < 128u)
                    v = *(const uint4*)(inb + (size_t)(gy*Wd+gx)*Cpad + ch*32 + g*8);
                *(uint4*)(As + (g*180+p)*8) = v;
            }
        }
        __syncthreads();
        const ushortT* wch = wpk + (size_t)(nt*NCH + ch)*(9*4*BN*8);
#pragma unroll
        for (int tp=0; tp<9; tp++){
            const int dy = tp/3, dx = tp - dy*3;
            short8v bf[NG];
#pragma unroll
            for (int n=0;n<NG;n++)
                bf[n] = *(const short8v*)(wch + ((size_t)(tp*4 + kg)*BN + n*16 + l15)*8);
#pragma unroll
            for (int mg=0;mg<8;mg++){
                short8v a = *(const short8v*)(As + (kg*180 + (mg+dy)*18 + l15+dx)*8);
#pragma unroll
                for (int n=0;n<NG;n++)
                    acc[mg][n] = __builtin_amdgcn_mfma_f32_16x16x32_bf16(a, bf[n], acc[mg][n], 0,0,0);
            }
        }
    }
    // epilogue: per-wave LDS transpose -> full coalesced NHWC rows (block covers all ocs)
    __syncthreads();
    ushortT* Ts = As + wv*1024;                       // 16px x 64 shorts
#pragma unroll
    for (int mg=0;mg<8;mg++){
        int gy = y0 + mg;
        ushortT* orow = outp + ((size_t)b*HWsz + gy*Wd + x0)*ocpad + ocbase;
#pragma unroll
        for (int n=0;n<NG;n++){
            int ocl = n*16 + l15;
            int oc  = ocbase + ocl;
            float bs = (bias && oc < cout) ? bias[oc] : 0.f;
#pragma unroll
            for (int j=0;j<4;j++){
                int pxj = kg*4 + j;
                float r = 0.f;
                if (oc < cout){ r = acc[mg][n][j] + bs; if (ACT) r = gelu_f(r); }
                int seg = ((ocl>>3) + pxj) & 7;
                Ts[pxj*64 + seg*8 + (ocl&7)] = f2b(r);
            }
        }
#pragma unroll
        for (int ps=0; ps < (BN+31)/32; ps++){
            int rpx = l & 15;
            int rs  = (l>>4) + ps*4;
            if (rs*8 < BN){
                int pseg = (rs + rpx) & 7;
                short8v v = *(const short8v*)(Ts + rpx*64 + pseg*8);
                *(short8v*)(orow + (size_t)rpx*ocpad + rs*8) = v;
            }
        }
    }
}

// ============ gemm1x1 v2: one block = 64 px x ALL output channels ============
// 4 waves = 4 oc-groups of NGW*16. in NHWC [b][p][Cpad], out NHWC [b][p][ocpad]. grid (256,1,B).
template<int NGW, int NCH>
__global__ __launch_bounds__(256) void gemm1x1_v2(
    const ushortT* __restrict__ inh, const ushortT* __restrict__ wpk,
    ushortT* __restrict__ outp, int cout, int ocpad)
{
    constexpr int BN = NGW*16;
    constexpr int Cpad = NCH*32;
    __shared__ __align__(16) ushortT Ts[4*16*64];

    const int tid = threadIdx.x;
    const int l = tid & 63, wv = tid >> 6, l15 = l & 15, kg = l >> 4;
    const int p0 = blockIdx.x*64;
    const int b  = blockIdx.z;
    const int nt = wv, ocbase = wv*BN;
    const ushortT* inb = inh + (size_t)b*HWsz*Cpad;

    f32x4 acc[4][NGW];
#pragma unroll
    for (int m=0;m<4;m++)
#pragma unroll
        for (int n=0;n<NGW;n++) acc[m][n] = (f32x4){0.f,0.f,0.f,0.f};

#pragma unroll
    for (int ch=0; ch<NCH; ch++){
        short8v a[4], bw[NGW];
#pragma unroll
        for (int mg=0; mg<4; mg++)
            a[mg] = *(const short8v*)(inb + (size_t)(p0 + mg*16 + l15)*Cpad + ch*32 + kg*8);
#pragma unroll
        for (int n=0;n<NGW;n++)
            bw[n] = *(const short8v*)(wpk + (((size_t)(nt*NCH + ch)*4 + kg)*BN + n*16 + l15)*8);
#pragma unroll
        for (int mg=0;mg<4;mg++)
#pragma unroll
            for (int n=0;n<NGW;n++)
                acc[mg][n] = __builtin_amdgcn_mfma_f32_16x16x32_bf16(a[mg], bw[n], acc[mg][n], 0,0,0);
    }
    ushortT* Tw = Ts + wv*1024;
#pragma unroll
    for (int mg=0;mg<4;mg++){
        ushortT* orow = outp + ((size_t)b*HWsz + p0 + mg*16)*ocpad + ocbase;
#pragma unroll
        for (int n=0;n<NGW;n++){
            int ocl = n*16 + l15;
            int oc  = ocbase + ocl;
#pragma unroll
            for (int j=0;j<4;j++){
                int pxj = kg*4 + j;
                float r = (oc < cout) ? acc[mg][n][j] : 0.f;
                int seg = ((ocl>>3) + pxj) & 7;
                Tw[pxj*64 + seg*8 + (ocl&7)] = f2b(r);
            }
        }
#pragma unroll
        for (int ps=0; ps < (BN+31)/32; ps++){
            int rpx = l & 15;
            int rs  = (l>>4) + ps*4;
            if (rs*8 < BN){
                int pseg = (rs + rpx) & 7;
                short8v v = *(const short8v*)(Tw + rpx*64 + pseg*8);
                *(short8v*)(orow + (size_t)rpx*ocpad + rs*8) = v;
            }
        }
    }
}

// ============ old conv3x3 (kept for q_dwconv, OMODE=2 bf16 NCHW out) ============
template<int NG, int NCH, int ACT, int OMODE, int NSPLIT, int XMAP>
__global__ __launch_bounds__(256,4) void conv3x3_mfma(
    const ushortT* __restrict__ inh,
    const ushortT* __restrict__ wpk1, const ushortT* __restrict__ wpk2,
    const float* __restrict__ bias1, const float* __restrict__ bias2,
    void* __restrict__ out1, void* __restrict__ out2,
    int cout, int ocpad)
{
    constexpr int BN = NG*16;
    constexpr int Cpad = NCH*32;
    __shared__ __align__(16) ushortT As[4*324*8];

    const int tid = threadIdx.x;
    const int l   = tid & 63;
    const int wv  = tid >> 6;
    const int l15 = l & 15;
    const int kg  = l >> 4;
    int tile = blockIdx.x, nt = blockIdx.y, b = blockIdx.z;
    const int tix = tile & 7, tiy = tile >> 3;

    const ushortT* wpk = wpk1; const float* bias = bias1; void* outv = out1;
    if (NSPLIT > 0 && nt >= NSPLIT){ nt -= NSPLIT; wpk = wpk2; bias = bias2; outv = out2; }

    f32x4 acc[4][NG];
#pragma unroll
    for (int m=0;m<4;m++)
#pragma unroll
        for (int n=0;n<NG;n++) acc[m][n] = (f32x4){0.f,0.f,0.f,0.f};

    const ushortT* inb = inh + (size_t)b*HWsz*Cpad;

    for (int ch=0; ch<NCH; ch++){
        __syncthreads();
#pragma unroll
        for (int g=0; g<4; g++){
            for (int p=tid; p<324; p+=256){
                int hy = p/18, hx = p - hy*18;
                int gy = tiy*16 + hy - 1, gx = tix*16 + hx - 1;
                uint4 v; v.x=0u; v.y=0u; v.z=0u; v.w=0u;
                if ((unsigned)gy < 128u && (unsigned)gx < 128u)
                    v = *(const uint4*)(inb + (size_t)(gy*Wd+gx)*Cpad + ch*32 + g*8);
                *(uint4*)(As + (g*324+p)*8) = v;
            }
        }
        __syncthreads();
        const ushortT* wch = wpk + (size_t)(nt*NCH + ch)*(9*4*BN*8);
#pragma unroll
        for (int tp=0; tp<9; tp++){
            const int dy = tp/3, dx = tp - dy*3;
            short8v a[4], bf[NG];
#pragma unroll
            for (int mg=0; mg<4; mg++){
                int p = (wv*4 + mg + dy)*18 + l15 + dx;
                a[mg] = *(const short8v*)(As + (kg*324 + p)*8);
            }
#pragma unroll
            for (int n=0;n<NG;n++)
                bf[n] = *(const short8v*)(wch + ((size_t)(tp*4 + kg)*BN + n*16 + l15)*8);
#pragma unroll
            for (int mg=0;mg<4;mg++)
#pragma unroll
                for (int n=0;n<NG;n++)
                    acc[mg][n] = __builtin_amdgcn_mfma_f32_16x16x32_bf16(a[mg], bf[n], acc[mg][n], 0,0,0);
        }
    }
    if (OMODE == 2){
        ushortT* out = (ushortT*)outv;
#pragma unroll
        for (int n=0;n<NG;n++){
            int oc = nt*BN + n*16 + l15;
            if (oc < cout){
                float bs = bias ? bias[oc] : 0.f;
#pragma unroll
                for (int mg=0;mg<4;mg++){
                    int gy = tiy*16 + wv*4 + mg;
                    int gx = tix*16 + kg*4;
                    ushort4v pk;
#pragma unroll
                    for (int j=0;j<4;j++){
                        float r = acc[mg][n][j] + bs;
                        if (ACT) r = gelu_f(r);
                        pk[j] = f2b(r);
                    }
                    *(ushort4v*)(out + ((size_t)b*cout + oc)*HWsz + gy*Wd + gx) = pk;
                }
            }
        }
    }
}

// ============ old gemm1x1 (kept for q0 / pv+po / fpo) ============
template<int NG, int NCH, int RES, int OMODE, int XMAP>
__global__ __launch_bounds__(256) void gemm1x1_mfma(
    const ushortT* __restrict__ inh, const ushortT* __restrict__ wpk, int wstride_z,
    const float* __restrict__ res1, const ushortT* __restrict__ res2b,
    void* __restrict__ outv, int cout, int ocpad)
{
    constexpr int BN = NG*16;
    constexpr int Cpad = NCH*32;
    constexpr int LSTR = (BN <= 64) ? 64 : 128;
    constexpr int MASK = LSTR/8 - 1;
    __shared__ __align__(16) ushortT TsS[(OMODE==1) ? 4*16*LSTR : 16];

    const int tid = threadIdx.x;
    const int l = tid & 63, wv = tid >> 6, l15 = l & 15, kg = l >> 4;
    int chunk = blockIdx.x, nt = blockIdx.y, b = blockIdx.z;
    const int p0 = chunk*256 + wv*64;
    const ushortT* inb = inh + (size_t)b*HWsz*Cpad;
    const ushortT* wp  = wpk + (size_t)b*wstride_z;

    f32x4 acc[4][NG];
#pragma unroll
    for (int m=0;m<4;m++)
#pragma unroll
        for (int n=0;n<NG;n++) acc[m][n] = (f32x4){0.f,0.f,0.f,0.f};

#pragma unroll
    for (int ch=0; ch<NCH; ch++){
        short8v a[4], bw[NG];
#pragma unroll
        for (int mg=0; mg<4; mg++)
            a[mg] = *(const short8v*)(inb + (size_t)(p0 + mg*16 + l15)*Cpad + ch*32 + kg*8);
#pragma unroll
        for (int n=0;n<NG;n++)
            bw[n] = *(const short8v*)(wp + (((size_t)(nt*NCH + ch)*4 + kg)*BN + n*16 + l15)*8);
#pragma unroll
        for (int mg=0;mg<4;mg++)
#pragma unroll
            for (int n=0;n<NG;n++)
                acc[mg][n] = __builtin_amdgcn_mfma_f32_16x16x32_bf16(a[mg], bw[n], acc[mg][n], 0,0,0);
    }
    if (OMODE == 0){
        float* out = (float*)outv;
#pragma unroll
        for (int n=0;n<NG;n++){
            int oc = nt*BN + n*16 + l15;
            if (oc < cout){
#pragma unroll
                for (int mg=0;mg<4;mg++){
                    int pix = p0 + mg*16 + kg*4;
                    size_t idx = ((size_t)b*cout + oc)*HWsz + pix;
                    float4 r;
                    r.x = acc[mg][n][0]; r.y = acc[mg][n][1];
                    r.z = acc[mg][n][2]; r.w = acc[mg][n][3];
                    if (RES>=1){ float4 q = *(const float4*)(res1+idx); r.x+=q.x;r.y+=q.y;r.z+=q.z;r.w+=q.w; }
                    if (RES>=2){
                        ushort4v q = *(const ushort4v*)(res2b+idx);
                        r.x+=b2f(q[0]); r.y+=b2f(q[1]); r.z+=b2f(q[2]); r.w+=b2f(q[3]);
                    }
                    *(float4*)(out + idx) = r;
                }
            }
        }
    } else {
        ushortT* outp = (ushortT*)outv;
        ushortT* Ts = TsS + wv*(16*LSTR);
#pragma unroll
        for (int mg=0;mg<4;mg++){
            ushortT* orow = outp + ((size_t)b*HWsz + p0 + mg*16)*ocpad + nt*BN;
#pragma unroll
            for (int n=0;n<NG;n++){
                int ocl = n*16 + l15;
                int oc  = nt*BN + ocl;
#pragma unroll
                for (int j=0;j<4;j++){
                    int pxj = kg*4 + j;
                    float r = (oc < cout) ? acc[mg][n][j] : 0.f;
                    int seg = ((ocl>>3) + pxj) & MASK;
                    Ts[pxj*LSTR + seg*8 + (ocl&7)] = f2b(r);
                }
            }
#pragma unroll
            for (int ps=0; ps < (BN+31)/32; ps++){
                int rpx = l & 15;
                int rs  = (l>>4) + ps*4;
                if (rs*8 < BN){
                    int pseg = (rs + rpx) & MASK;
                    short8v v = *(const short8v*)(Ts + rpx*LSTR + pseg*8);
                    *(short8v*)(orow + (size_t)rpx*ocpad + rs*8) = v;
                }
            }
        }
    }
}

// ============ head 1x1 (96 -> NOUT), NHWC bf16 in, NCHW fp32 out ============
template<int NOUT>
__global__ __launch_bounds__(256) void head1x1_kernel(
    const ushortT* __restrict__ inh, const float* __restrict__ w,
    const float* __restrict__ bias, float* __restrict__ out)
{
    __shared__ float lw[NOUT*96];
    const int tid = threadIdx.x;
    for (int t=tid; t<NOUT*96; t+=256) lw[t] = w[t];
    __syncthreads();
    const int p = blockIdx.x*256 + tid;
    const int b = blockIdx.y;
    const ushortT* ip = inh + ((size_t)b*HWsz + p)*96;
    float v[96];
#pragma unroll
    for (int g=0; g<12; g++){
        short8v s = *(const short8v*)(ip + g*8);
#pragma unroll
        for (int i=0;i<8;i++) v[g*8+i] = b2f((ushortT)s[i]);
    }
#pragma unroll
    for (int oc=0; oc<NOUT; oc++){
        float acc = bias[oc];
#pragma unroll
        for (int c=0;c<96;c++) acc += v[c]*lw[oc*96+c];
        out[((size_t)b*NOUT + oc)*HWsz + p] = acc;
    }
}

// ============ fused: Lr conv3x3(1->96)+bias+GELU + LayerNorm(nL) -> illh bf16 NHWC ============
__global__ __launch_bounds__(256) void lrein_ln_kernel(
    const float* __restrict__ L, const float* __restrict__ w,
    const float* __restrict__ bias, const float* __restrict__ lnw,
    const float* __restrict__ lnb, ushortT* __restrict__ outh)
{
    __shared__ float sw[864], sb[96], sn1[96], sn2[96];
    const int tid = threadIdx.x;
    for (int t=tid; t<864; t+=256) sw[t] = w[t];
    if (tid < 96){ sb[tid]=bias[tid]; sn1[tid]=lnw[tid]; sn2[tid]=lnb[tid]; }
    __syncthreads();
    const int p = blockIdx.x*256 + tid;
    const int b = blockIdx.y;
    const int y = p>>7, x = p&127;
    const float* ib = L + (size_t)b*HWsz;
    float win[9];
#pragma unroll
    for (int dy=0;dy<3;dy++)
#pragma unroll
        for (int dx=0;dx<3;dx++){
            int gy=y+dy-1, gx=x+dx-1;
            win[dy*3+dx] = ((unsigned)gy<128u && (unsigned)gx<128u) ? ib[gy*Wd+gx] : 0.f;
        }
    float v[96]; float s=0.f;
#pragma unroll
    for (int c=0;c<96;c++){
        float a = sb[c];
#pragma unroll
        for (int t=0;t<9;t++) a += win[t]*sw[c*9+t];
        a = gelu_f(a);
        v[c]=a; s+=a;
    }
    const float mu = s*(1.f/96.f);
    float s2=0.f;
#pragma unroll
    for (int c=0;c<96;c++){ float d=v[c]-mu; s2+=d*d; }
    const float inv = 1.f/sqrtf(s2*(1.f/96.f)+1e-5f);
    ushortT* op = outh + ((size_t)b*HWsz + p)*96;
#pragma unroll
    for (int g=0; g<12; g++){
        uint4 pk; uintT w4[4];
#pragma unroll
        for (int i=0;i<4;i++){
            float r0 = (v[g*8+2*i]-mu)*inv*sn1[g*8+2*i]+sn2[g*8+2*i];
            float r1 = (v[g*8+2*i+1]-mu)*inv*sn1[g*8+2*i+1]+sn2[g*8+2*i+1];
            w4[i] = (uintT)f2b(r0) | ((uintT)f2b(r1)<<16);
        }
        pk.x=w4[0]; pk.y=w4[1]; pk.z=w4[2]; pk.w=w4[3];
        *(uint4*)(op + g*8) = pk;
    }
}

// ============ LayerNorm: NCHW fp32 -> NHWC bf16 ============
__global__ __launch_bounds__(256) void ln_n2n_kernel(
    const float* __restrict__ in, const float* __restrict__ w,
    const float* __restrict__ bias, ushortT* __restrict__ outh)
{
    const int p = blockIdx.x*256+threadIdx.x;
    const int b = blockIdx.y;
    const float* ip = in + (size_t)b*96*HWsz + p;
    float v[96]; float s=0.f;
#pragma unroll
    for(int c=0;c<96;c++){ v[c]=ip[(size_t)c*HWsz]; s+=v[c]; }
    const float mu = s*(1.f/96.f);
    float s2=0.f;
#pragma unroll
    for(int c=0;c<96;c++){ float d=v[c]-mu; s2+=d*d; }
    const float inv = 1.f/sqrtf(s2*(1.f/96.f)+1e-5f);
    ushortT* op = outh + ((size_t)b*HWsz + p)*96;
#pragma unroll
    for (int g=0; g<12; g++){
        uint4 pk; uintT w4[4];
#pragma unroll
        for (int i=0;i<4;i++){
            float r0 = (v[g*8+2*i]-mu)*inv*w[g*8+2*i]+bias[g*8+2*i];
            float r1 = (v[g*8+2*i+1]-mu)*inv*w[g*8+2*i+1]+bias[g*8+2*i+1];
            w4[i] = (uintT)f2b(r0) | ((uintT)f2b(r1)<<16);
        }
        pk.x=w4[0]; pk.y=w4[1]; pk.z=w4[2]; pk.w=w4[3];
        *(uint4*)(op + g*8) = pk;
    }
}

// ============ Rr 3->96, 8 oc per block -> bf16 NCHW ============
__global__ __launch_bounds__(256) void conv3x3_rr_kernel(
    const float* __restrict__ in, const float* __restrict__ w,
    const float* __restrict__ bias, ushortT* __restrict__ out)
{
    __shared__ float sw[216], sb[8];
    const int oc0 = blockIdx.y*8;
    if (threadIdx.x < 216) sw[threadIdx.x] = w[(size_t)oc0*27 + threadIdx.x];
    if (threadIdx.x < 8)   sb[threadIdx.x] = bias[oc0 + threadIdx.x];
    __syncthreads();
    const int p = blockIdx.x*256+threadIdx.x;
    const int b = blockIdx.z;
    const int y=p>>7, x=p&127;
    const float* ib = in + (size_t)b*3*HWsz;
    float win[27];
#pragma unroll
    for (int ci=0;ci<3;ci++)
#pragma unroll
        for (int dy=0;dy<3;dy++)
#pragma unroll
            for (int dx=0;dx<3;dx++){
                int gy=y+dy-1, gx=x+dx-1;
                win[ci*9+dy*3+dx] = ((unsigned)gy<128u && (unsigned)gx<128u)
                    ? ib[(size_t)ci*HWsz + gy*Wd+gx] : 0.f;
            }
#pragma unroll
    for (int i=0;i<8;i++){
        float acc = sb[i];
#pragma unroll
        for (int t=0;t<27;t++) acc += win[t]*sw[i*27+t];
        out[((size_t)b*96 + oc0+i)*HWsz + p] = f2b(acc);
    }
}

// ============ depthwise 3x3 NHWC bf16; k-half -> bf16 NCHW, v-half -> bf16 NHWC ============
__global__ __launch_bounds__(256) void dw_nhwc_kernel(
    const ushortT* __restrict__ inh, const float* __restrict__ w,
    ushortT* __restrict__ kout, ushortT* __restrict__ vouth)
{
    const int p = blockIdx.x*256+threadIdx.x;
    const int c0 = blockIdx.y*8;
    const int b = blockIdx.z;
    const int y=p>>7, x=p&127;
    float lw[72];
#pragma unroll
    for (int i=0;i<8;i++)
#pragma unroll
        for (int t=0;t<9;t++) lw[i*9+t] = w[(size_t)(c0+i)*9 + t];
    const ushortT* ib = inh + (size_t)b*HWsz*192;
    float acc[8];
#pragma unroll
    for (int i=0;i<8;i++) acc[i]=0.f;
#pragma unroll
    for(int dy=0;dy<3;dy++){
        int gy=y+dy-1;
        if((unsigned)gy<128u){
#pragma unroll
            for(int dx=0;dx<3;dx++){
                int gx=x+dx-1;
                if((unsigned)gx<128u){
                    short8v s = *(const short8v*)(ib + (size_t)(gy*Wd+gx)*192 + c0);
#pragma unroll
                    for (int i=0;i<8;i++) acc[i] += b2f((ushortT)s[i])*lw[i*9+dy*3+dx];
                }
            }
        }
    }
    if (c0 < 96){
#pragma unroll
        for (int i=0;i<8;i++)
            kout[((size_t)b*96 + c0+i)*HWsz + p] = f2b(acc[i]);
    } else {
        ushortT* op = vouth + ((size_t)b*HWsz + p)*96 + (c0-96);
        uint4 pk;
        pk.x = (uintT)f2b(acc[0]) | ((uintT)f2b(acc[1])<<16);
        pk.y = (uintT)f2b(acc[2]) | ((uintT)f2b(acc[3])<<16);
        pk.z = (uintT)f2b(acc[4]) | ((uintT)f2b(acc[5])<<16);
        pk.w = (uintT)f2b(acc[6]) | ((uintT)f2b(acc[7])<<16);
        *(uint4*)op = pk;
    }
}

// ============ row L2-norm reciprocals for q/k (bf16 NCHW) ============
__global__ __launch_bounds__(256) void rownorm_bf16_kernel(
    const ushortT* __restrict__ qb, const ushortT* __restrict__ kb,
    float* __restrict__ invqk)
{
    __shared__ float red[256];
    const int r = blockIdx.x;       // 0..767
    const ushortT* ip = (r < 384) ? (qb + (size_t)r*HWsz) : (kb + (size_t)(r-384)*HWsz);
    float s=0.f;
    const ushortT* tp = ip + threadIdx.x*64;
#pragma unroll
    for (int g=0; g<8; g++){
        short8v v = *(const short8v*)(tp + g*8);
#pragma unroll
        for (int i=0;i<8;i++){ float f = b2f((ushortT)v[i]); s += f*f; }
    }
    red[threadIdx.x]=s; __syncthreads();
    for(int st=128; st>0; st>>=1){
        if(threadIdx.x<st) red[threadIdx.x]+=red[threadIdx.x+st];
        __syncthreads();
    }
    if(threadIdx.x==0) invqk[r] = 1.f/fmaxf(sqrtf(red[0]), 1e-12f);
}

// ============ QK^T Gram via MFMA 32x32x16 ============
__global__ __launch_bounds__(256) void qk_mfma_kernel(
    const ushortT* __restrict__ qb, const ushortT* __restrict__ kb,
    float* __restrict__ part)
{
    const int tid = threadIdx.x;
    const int l = tid & 63, wv = tid >> 6;
    const int chunk = blockIdx.x*4 + wv;          // 0..31
    const int bh = blockIdx.y, b = bh>>2, h = bh&3;
    const int ch = min(l & 31, 23);
    const int kh = (l >> 5)*8;
    const ushortT* qp = qb + ((size_t)b*96 + h*24 + ch)*HWsz + chunk*512 + kh;
    const ushortT* kp = kb + ((size_t)b*96 + h*24 + ch)*HWsz + chunk*512 + kh;
    f32x16 acc;
#pragma unroll
    for (int r=0;r<16;r++) acc[r]=0.f;
    for (int ks=0; ks<32; ks++){
        short8v a  = *(const short8v*)(qp + ks*16);
        short8v bb = *(const short8v*)(kp + ks*16);
        acc = __builtin_amdgcn_mfma_f32_32x32x16_bf16(a, bb, acc, 0,0,0);
    }
    float* op = part + ((size_t)chunk*16 + bh)*1024;
    const int col = l & 31;
#pragma unroll
    for (int r=0;r<16;r++){
        int row = (r&3) + 8*(r>>2) + 4*(l>>5);
        op[row*32 + col] = acc[r];
    }
}

__global__ void qk_reduce_kernel(const float* __restrict__ part, float* __restrict__ out)
{
    int idx = blockIdx.x*256+threadIdx.x;      // 16*1024
    float s=0.f;
    for(int c=0;c<32;c++) s += part[(size_t)c*16384 + idx];
    out[idx]=s;
}

// ============ softmax over 24 cols (norms + temp folded) ============
__global__ __launch_bounds__(576) void softmax_kernel(
    const float* __restrict__ raw, const float* __restrict__ invq,
    const float* __restrict__ invk, const float* __restrict__ temp,
    float* __restrict__ attn)
{
    __shared__ float l[576];
    const int bh=blockIdx.x, b=bh>>2, h=bh&3;
    const int tid=threadIdx.x;
    const int i=tid/24, j=tid-i*24;
    l[tid] = raw[(size_t)bh*1024 + i*32 + j] * invq[b*96+h*24+i] * invk[b*96+h*24+j] * temp[h];
    __syncthreads();
    if(tid<24){
        float m=-1e30f;
#pragma unroll
        for(int jj=0;jj<24;jj++) m = fmaxf(m, l[tid*24+jj]);
        float e[24]; float s=0.f;
#pragma unroll
        for(int jj=0;jj<24;jj++){ e[jj]=__expf(l[tid*24+jj]-m); s+=e[jj]; }
        float isv = 1.f/s;
#pragma unroll
        for(int jj=0;jj<24;jj++) attn[(size_t)bh*576 + tid*24 + jj] = e[jj]*isv;
    }
}

// ============ M_b = po_w @ blockdiag(attn_b), packed to B-frag bf16 ============
__global__ __launch_bounds__(256) void mkM_kernel(
    const float* __restrict__ attn, const float* __restrict__ po_w,
    ushortT* __restrict__ Mpk)
{
    const int b = blockIdx.x;
    for (int e = threadIdx.x; e < 9216; e += 256){
        int oc = e / 96, d = e - oc*96;
        int h = d / 24, dl = d - h*24;
        const float* aw = attn + ((size_t)(b*4+h))*576 + dl;
        const float* pw = po_w + (size_t)oc*96 + h*24;
        float s = 0.f;
#pragma unroll
        for (int c=0;c<24;c++) s += pw[c]*aw[c*24];
        int ch = d>>5, kg = (d>>3)&3, j = d&7;
        Mpk[(size_t)b*9216 + ((size_t)(ch*4+kg)*96 + oc)*8 + j] = f2b(s);
    }
}

extern "C" void kernel_launch(void* const* d_in, const int* in_sizes, int n_in,
                              void* d_out, int out_size, void* d_ws, size_t ws_size,
                              hipStream_t stream)
{
    const float* x     = (const float*)d_in[0];
    const float* Lc_w1 = (const float*)d_in[1];
    const float* Lc_b1 = (const float*)d_in[2];
    const float* Lc_w2 = (const float*)d_in[3];
    const float* Lc_b2 = (const float*)d_in[4];
    const float* Rc_w1 = (const float*)d_in[5];
    const float* Rc_b1 = (const float*)d_in[6];
    const float* Rc_w2 = (const float*)d_in[7];
    const float* Rc_b2 = (const float*)d_in[8];
    const float* Lr_w  = (const float*)d_in[9];
    const float* Lr_b  = (const float*)d_in[10];
    const float* Rr_w  = (const float*)d_in[11];
    const float* Rr_b  = (const float*)d_in[12];
    const float* n1_w  = (const float*)d_in[13];
    const float* n1_b  = (const float*)d_in[14];
    const float* nL_w  = (const float*)d_in[15];
    const float* nL_b  = (const float*)d_in[16];
    const float* n2_w  = (const float*)d_in[17];
    const float* n2_b  = (const float*)d_in[18];
    const float* temp  = (const float*)d_in[19];
    const float* q_w   = (const float*)d_in[20];
    const float* qd_w  = (const float*)d_in[21];
    const float* kv_w  = (const float*)d_in[22];
    const float* kvd_w = (const float*)d_in[23];
    const float* po_w  = (const float*)d_in[24];
    const float* pi_w  = (const float*)d_in[25];
    const float* fdw_w = (const float*)d_in[26];
    const float* fpo_w = (const float*)d_in[27];

    char* base = (char*)d_ws;
    ushortT* xh   = (ushortT*)(base + 0);
    ushortT* f0h  = (ushortT*)(base + 0);
    ushortT* Lh   = (ushortT*)(base + 33554432);
    ushortT* kv0h = (ushortT*)(base + 33554432);
    ushortT* f1h  = (ushortT*)(base + 33554432);
    ushortT* Rh   = (ushortT*)(base + 67108864);
    ushortT* vh   = (ushortT*)(base + 67108864);
    ushortT* x2nh = (ushortT*)(base + 67108864);
    ushortT* illh = (ushortT*)(base + 79691776);
    ushortT* xnh  = (ushortT*)(base + 92274688);
    ushortT* q0h  = (ushortT*)(base + 104857600);
    ushortT* qb   = (ushortT*)(base + 117440512);
    float*   x1   = (float*)(base + 117440512);
    ushortT* kb   = (ushortT*)(base + 142606336);
    ushortT* Bb   = (ushortT*)(base + 155189248);
    char* smb = base + 167772160;
    ushortT* wpkL = (ushortT*)smb;   smb += 165888;
    ushortT* wpkR = (ushortT*)smb;   smb += 165888;
    ushortT* wpkQ = (ushortT*)smb;   smb += 165888;
    ushortT* wpkF = (ushortT*)smb;   smb += 1179648;
    ushortT* wq0  = (ushortT*)smb;   smb += 18432;
    ushortT* wkv  = (ushortT*)smb;   smb += 36864;
    ushortT* wpi  = (ushortT*)smb;   smb += 49152;
    ushortT* wfpo = (ushortT*)smb;   smb += 49152;
    ushortT* Mpk  = (ushortT*)smb;   smb += 73728;
    float* invqk  = (float*)smb;     smb += 3072;
    float* part   = (float*)smb;     smb += 2097152;
    float* araw   = (float*)smb;     smb += 65536;
    float* attn   = (float*)smb;     smb += 36864;

    float* out_x = (float*)d_out;
    float* out_L = out_x + (size_t)4*96*HWsz;
    float* out_R = out_L + (size_t)4*HWsz;

    dim3 blk(256);

    // ---- packing + input convert ----
    hipLaunchKernelGGL(pack_all_kernel, dim3(3576), blk, 0, stream,
        Lc_w1, Rc_w1, qd_w, fdw_w, q_w, kv_w, pi_w, fpo_w,
        wpkL, wpkR, wpkQ, wpkF, wq0, wkv, wpi, wfpo);
    hipLaunchKernelGGL(tonhwc_kernel, dim3(64,4), blk, 0, stream, x, xh);

    // ---- Retinex heads (Lc+Rc in one all-oc kernel) ----
    hipLaunchKernelGGL((conv3x3_v2<3,3,1,1>), dim3(128,1,4), blk, 0, stream,
        xh, wpkL, wpkR, Lc_b1, Rc_b1, Lh, Rh, 96, 96);
    hipLaunchKernelGGL((head1x1_kernel<1>), dim3(64,4), blk, 0, stream, Lh, Lc_w2, Lc_b2, out_L);
    hipLaunchKernelGGL((head1x1_kernel<3>), dim3(64,4), blk, 0, stream, Rh, Rc_w2, Rc_b2, out_R);
    hipLaunchKernelGGL(lrein_ln_kernel, dim3(64,4), blk, 0, stream, out_L, Lr_w, Lr_b, nL_w, nL_b, illh);
    hipLaunchKernelGGL(conv3x3_rr_kernel, dim3(64,12,4), blk, 0, stream, out_R, Rr_w, Rr_b, Bb);

    // ---- n1 norm ----
    hipLaunchKernelGGL(ln_n2n_kernel, dim3(64,4), blk, 0, stream, x, n1_w, n1_b, xnh);

    // ---- q path ----
    hipLaunchKernelGGL((gemm1x1_mfma<6,3,0,1,0>), dim3(64,1,4), blk, 0, stream,
        illh, wq0, 0, nullptr, nullptr, (void*)q0h, 96, 96);
    hipLaunchKernelGGL((conv3x3_mfma<2,3,0,2,0,0>), dim3(64,3,4), blk, 0, stream,
        q0h, wpkQ, wpkQ, nullptr, nullptr, (void*)qb, (void*)qb, 96, 0);
    // ---- kv path ----
    hipLaunchKernelGGL((gemm1x1_v2<3,3>), dim3(256,1,4), blk, 0, stream,
        xnh, wkv, kv0h, 192, 192);
    hipLaunchKernelGGL(dw_nhwc_kernel, dim3(64,24,4), blk, 0, stream, kv0h, kvd_w, kb, vh);

    // ---- attention ----
    hipLaunchKernelGGL(rownorm_bf16_kernel, dim3(768), blk, 0, stream, qb, kb, invqk);
    hipLaunchKernelGGL(qk_mfma_kernel, dim3(8,16), blk, 0, stream, qb, kb, part);
    hipLaunchKernelGGL(qk_reduce_kernel, dim3(64), blk, 0, stream, part, araw);
    hipLaunchKernelGGL(softmax_kernel, dim3(16), dim3(576), 0, stream, araw, invqk, invqk+384, temp, attn);
    hipLaunchKernelGGL(mkM_kernel, dim3(4), blk, 0, stream, attn, po_w, Mpk);
    // fused pv+po: x1 = x + M_b @ v
    hipLaunchKernelGGL((gemm1x1_mfma<6,3,1,0,0>), dim3(64,1,4), blk, 0, stream,
        vh, Mpk, 9216, x, nullptr, (void*)x1, 96, 0);

    // ---- FFN ----
    hipLaunchKernelGGL(ln_n2n_kernel, dim3(64,4), blk, 0, stream, x1, n2_w, n2_b, x2nh);
    hipLaunchKernelGGL((gemm1x1_v2<4,3>), dim3(256,1,4), blk, 0, stream,
        x2nh, wpi, f0h, 255, 256);
    hipLaunchKernelGGL((conv3x3_v2<4,8,1,0>), dim3(128,1,4), blk, 0, stream,
        f0h, wpkF, wpkF, nullptr, nullptr, f1h, f1h, 255, 256);
    hipLaunchKernelGGL((gemm1x1_mfma<6,8,2,0,0>), dim3(64,1,4), blk, 0, stream,
        f1h, wfpo, 0, x1, Bb, (void*)out_x, 96, 0);
}